// Round 4
// baseline (948.525 us; speedup 1.0000x reference)
//
#include <hip/hip_runtime.h>
#include <stdint.h>

// ---------------------------------------------------------------------------
// VQ-VAE forward on MI355X. Round 8: vqm split. R7 vqm was parallelism-
// starved: 136KB LDS -> 1 block/CU, 4 waves (Occ 10%), MFMA cycles only
// ~6.6us of 121us; staging drains, gather writes (827 GB/s) and hist atomics
// all sat naked on the critical path. R8: (a) vqm_kernel = partial argmin,
// grid 512x4 (2048 blocks, 128 rows x 128 codes each, R6-proven 2-barrier
// K-loop, 18.6KB LDS -> 4 blocks/CU); writes 2MB of (val,key) partials only.
// (b) vqg_kernel = merge partials + hist + zq/zqb gather at high occupancy
// (2048 blocks, write-BW-bound). Distances bit-identical to R7; global
// first-min tie-break preserved. Rest identical to R7.
// ---------------------------------------------------------------------------

typedef unsigned short bfraw;
typedef __attribute__((ext_vector_type(8))) short s16x8;
typedef __attribute__((ext_vector_type(4))) float f32x4;

__device__ __forceinline__ float bflo(unsigned int u) {
    union { unsigned int i; float f; } v; v.i = u << 16; return v.f;
}
__device__ __forceinline__ float bfhi(unsigned int u) {
    union { unsigned int i; float f; } v; v.i = u & 0xFFFF0000u; return v.f;
}
__device__ __forceinline__ bfraw f2bf(float f) {
    union { float f; unsigned int i; } v; v.f = f;
    unsigned int r = v.i + 0x7FFFu + ((v.i >> 16) & 1u);   // RNE
    return (bfraw)(r >> 16);
}

// async 16B global->LDS. LDS dest: wave-uniform base + lane*16; global src per-lane.
__device__ __forceinline__ void gl_lds16(const void* g, void* l) {
    auto gp = reinterpret_cast<const __attribute__((address_space(1))) unsigned int*>(
        reinterpret_cast<uintptr_t>(g));
    auto lp = reinterpret_cast<__attribute__((address_space(3))) unsigned int*>(
        reinterpret_cast<uintptr_t>(l));
    __builtin_amdgcn_global_load_lds(gp, lp, 16, 0, 0);
}

// --- weight transform (fp32, [tap][ci][co]) for dec2
__global__ void wt_kernel(const float* __restrict__ w, float* __restrict__ wt,
                          int Cout, int Cin, int KH, int KW, int transposed) {
    int n = Cout * Cin * KH * KW;
    for (int i = blockIdx.x * blockDim.x + threadIdx.x; i < n; i += gridDim.x * blockDim.x) {
        int co = i % Cout; int t = i / Cout;
        int ci = t % Cin;  int tap = t / Cin;
        int kw = tap % KW; int kh = tap / KW;
        float v = transposed ? w[(((long)ci * Cout + co) * KH + kh) * KW + kw]
                             : w[(((long)co * Cin + ci) * KH + kh) * KW + kw];
        wt[i] = v;
    }
}

// --- weight transform (bf16, [co][tap][ci]) for MFMA convs (B as [n][k]);
//     with KH=KW=1 also converts emb[512][256] to bf16 B layout.
__global__ void wtb_kernel(const float* __restrict__ w, bfraw* __restrict__ wt,
                           int Cout, int Cin, int KH, int KW, int transposed) {
    int n = Cout * Cin * KH * KW;
    int NT = KH * KW;
    for (int i = blockIdx.x * blockDim.x + threadIdx.x; i < n; i += gridDim.x * blockDim.x) {
        int ci = i % Cin; int t = i / Cin;
        int tap = t % NT; int co = t / NT;
        int kh = tap / KW, kw = tap % KW;
        float v = transposed ? w[(((long)ci * Cout + co) * KH + kh) * KW + kw]
                             : w[(((long)co * Cin + ci) * KH + kh) * KW + kw];
        wt[i] = f2bf(v);
    }
}

// --- enc1 weight pack: wb1[co][k64], k=(kh*4+kw)*3+ci (48 real, 16 zero)
__global__ void wb1_kernel(const float* __restrict__ w, bfraw* __restrict__ wt) {
    int i = blockIdx.x * 256 + threadIdx.x;
    if (i >= 4096) return;
    int k = i & 63, co = i >> 6;
    bfraw v = 0;
    if (k < 48) {
        int ci = k % 3, tap = k / 3, kh = tap >> 2, kw = tap & 3;
        v = f2bf(w[(((long)co * 3 + ci) * 4 + kh) * 4 + kw]);
    }
    wt[(long)co * 64 + k] = v;
}

// --- enc1 im2col: x NCHW fp32 -> A0[pos][64] bf16 (48 patch vals + 16 zeros)
__global__ __launch_bounds__(256) void xpack_kernel(const float* __restrict__ x,
                                                    bfraw* __restrict__ a0) {
    int pos = blockIdx.x * 256 + threadIdx.x;        // 262144
    int ow = pos & 127, oh = (pos >> 7) & 127, n = pos >> 14;
    __align__(16) bfraw v[64];
#pragma unroll
    for (int i = 0; i < 64; ++i) v[i] = 0;
#pragma unroll
    for (int kh = 0; kh < 4; ++kh) {
        int ih = 2 * oh - 1 + kh; if ((unsigned)ih >= 256u) continue;
#pragma unroll
        for (int kw = 0; kw < 4; ++kw) {
            int iw = 2 * ow - 1 + kw; if ((unsigned)iw >= 256u) continue;
#pragma unroll
            for (int ci = 0; ci < 3; ++ci)
                v[(kh * 4 + kw) * 3 + ci] =
                    f2bf(x[(((long)n * 3 + ci) * 256 + ih) * 256 + iw]);
        }
    }
    uint4* dst = (uint4*)(a0 + (long)pos * 64);
    const uint4* src = (const uint4*)v;
#pragma unroll
    for (int i = 0; i < 8; ++i) dst[i] = src[i];
}

// --- emb row norms
__global__ void embsq_kernel(const float* __restrict__ emb, float* __restrict__ esq) {
    int k = blockIdx.x, lane = threadIdx.x;
    float s = 0.f;
    for (int d = lane; d < 256; d += 64) { float v = emb[k * 256 + d]; s += v * v; }
    for (int o = 32; o; o >>= 1) s += __shfl_down(s, o, 64);
    if (lane == 0) esq[k] = s;
}

// ---------------------------------------------------------------------------
// MFMA implicit GEMM. C[MxN] = A[MxK]*B[KxN].
// ---------------------------------------------------------------------------
template<int BM, int BN, int WM, int WN, bool TR, bool RELU, bool OUTF32, bool DUALB>
__global__ __launch_bounds__(256) void igemm_kernel(
    const bfraw* __restrict__ in, const bfraw* __restrict__ wt,
    const float* __restrict__ bias, void* __restrict__ outv,
    bfraw* __restrict__ outb, const bfraw* __restrict__ zp,
    int Hin, int Win, int Cin, int sf, int NTW, int Ksteps,
    int lw, int lh, int N, int KW, int pad, int py, int px,
    unsigned long long pack)
{
    constexpr int APASS = BM / 64, BPASS = BN / 64;
    __shared__ __align__(16) bfraw ldsA[BM * 32];
    __shared__ __align__(16) bfraw ldsB[BN * 32];
    const int tid = threadIdx.x, lane = tid & 63, wv = tid >> 6;
    const int wm = wv / WN, wn = wv % WN;
    const int lrow = lane >> 2, lkof = (lane & 3) * 8;
    const int blockM = blockIdx.x, n0 = blockIdx.y * BN;
    const int Wm1 = (1 << lw) - 1, Hm1 = (1 << lh) - 1;

    long baseA[APASS]; int ihb[APASS], iwb[APASS];
#pragma unroll
    for (int p = 0; p < APASS; ++p) {
        int m = p * 64 + wv * 16 + lrow;
        int pos = blockM * BM + m;
        int ow = pos & Wm1; int t = pos >> lw;
        int oh = t & Hm1;   int nb = t >> lh;
        ihb[p] = oh * sf; iwb[p] = ow * sf;
        baseA[p] = ((long)(nb * Hin + ihb[p]) * Win + iwb[p]) * (long)Cin + lkof;
    }
    long baseB[BPASS];
#pragma unroll
    for (int p = 0; p < BPASS; ++p) {
        int nl = p * 64 + wv * 16 + lrow;
        baseB[p] = (long)(n0 + nl) * ((long)NTW * Cin) + lkof;
    }

    f32x4 acc[4][4];
#pragma unroll
    for (int i = 0; i < 4; ++i)
#pragma unroll
        for (int j = 0; j < 4; ++j) acc[i][j] = (f32x4)0.f;

    int ci0 = 0, tslot = 0, dy, dx, wk;
    if (TR) {
        unsigned e = (unsigned)pack & 0xFFFFu;
        dy = (int)((e >> 8) & 3) - 1; dx = (int)((e >> 4) & 3) - 1; wk = (int)(e & 15u);
    } else { dy = -pad; dx = -pad; wk = 0; }

    const int quad = lane >> 4, r16 = lane & 15;

    for (int ks = 0; ks < Ksteps; ++ks) {
        long offA = ((long)(dy * Win + dx)) * Cin + ci0;
        long offB = (long)wk * Cin + ci0;
#pragma unroll
        for (int p = 0; p < APASS; ++p) {
            int ih = ihb[p] + dy, iw = iwb[p] + dx;
            bool ok = ((unsigned)ih < (unsigned)Hin) & ((unsigned)iw < (unsigned)Win);
            const bfraw* g = ok ? (in + baseA[p] + offA) : (zp + lkof);
            gl_lds16(g, &ldsA[(p * 64 + wv * 16) * 32]);
        }
#pragma unroll
        for (int p = 0; p < BPASS; ++p)
            gl_lds16(wt + baseB[p] + offB, &ldsB[(p * 64 + wv * 16) * 32]);
        __syncthreads();
        s16x8 af[4], bf[4];
#pragma unroll
        for (int i = 0; i < 4; ++i)
            af[i] = *(const s16x8*)&ldsA[(wm * 64 + i * 16 + r16) * 32 + quad * 8];
#pragma unroll
        for (int j = 0; j < 4; ++j)
            bf[j] = *(const s16x8*)&ldsB[(wn * 64 + j * 16 + r16) * 32 + quad * 8];
#pragma unroll
        for (int i = 0; i < 4; ++i)
#pragma unroll
            for (int j = 0; j < 4; ++j)
                acc[i][j] = __builtin_amdgcn_mfma_f32_16x16x32_bf16(af[i], bf[j], acc[i][j], 0, 0, 0);
        __syncthreads();
        ci0 += 32;
        if (ci0 == Cin) {
            ci0 = 0; ++tslot;
            if (TR) {
                unsigned e = (unsigned)(pack >> (tslot * 16)) & 0xFFFFu;
                dy = (int)((e >> 8) & 3) - 1; dx = (int)((e >> 4) & 3) - 1; wk = (int)(e & 15u);
            } else { ++wk; ++dx; if (dx == KW - pad) { dx = -pad; ++dy; } }
        }
    }

#pragma unroll
    for (int j = 0; j < 4; ++j) {
        int col = wn * 64 + j * 16 + r16; int ng = n0 + col;
        float bv = bias[ng];
#pragma unroll
        for (int i = 0; i < 4; ++i) {
            int mb = wm * 64 + i * 16 + quad * 4;
#pragma unroll
            for (int r = 0; r < 4; ++r) {
                int pos2 = blockM * BM + mb + r;
                long oaddr;
                if (TR) {
                    int ow2 = pos2 & Wm1; int t = pos2 >> lw;
                    int oh2 = t & Hm1;    int nb = t >> lh;
                    int oh = 2 * oh2 + py, ow = 2 * ow2 + px;
                    oaddr = ((long)(((nb << (lh + 1)) + oh) << (lw + 1)) + ow) * N + ng;
                } else {
                    oaddr = (long)pos2 * N + ng;
                }
                float v = acc[i][j][r] + bv;
                if (RELU) v = fmaxf(v, 0.f);
                if (OUTF32) {
                    ((float*)outv)[oaddr] = v;
                    if (DUALB) outb[oaddr] = f2bf(v);
                } else {
                    ((bfraw*)outv)[oaddr] = f2bf(v);
                }
            }
        }
    }
}

// ---------------------------------------------------------------------------
// dec2: convT k3 s1 p1, 64->3ch, fp32 NCHW out.
// Block = 16x16 output tile (grid 16 n * 256 tiles = 4096). Thread = 1 px.
// Full-channel staging: 18x18 halo x 64ch = 41,472 B LDS, single buffer, ONE
// barrier. Each 128B pixel record fetched exactly once (rows contiguous).
// 128B record == 32 banks -> sub-slot XOR swizzle by (px&7) on BOTH sides.
// OOB halo -> zero page. Weights: uniform -> scalar loads.
// ---------------------------------------------------------------------------
__global__ __launch_bounds__(256) void dec2_kernel(
    const bfraw* __restrict__ in, const float* __restrict__ wt,
    const float* __restrict__ bias, float* __restrict__ out,
    const bfraw* __restrict__ zp) {
    __shared__ __align__(16) bfraw tile[18 * 18 * 64];   // 41,472 B
    const int tid = threadIdx.x;
    const int b = blockIdx.x;
    const int n = b >> 8, t8 = b & 255;
    const int r0 = (t8 >> 4) * 16, c0 = (t8 & 15) * 16;
    const int wv = tid >> 6;
    const long nbase = (long)n * 65536;                  // px index base of image

    // ---- stage: 2592 segs of 16B (10 full passes + 32 tail) ----
#pragma unroll
    for (int k = 0; k < 10; ++k) {
        int t = k * 256 + tid;
        int px = t >> 3, d = t & 7;
        int pr = px / 18, pc = px - pr * 18;
        int ih = r0 - 1 + pr, iw = c0 - 1 + pc;
        bool ok = ((unsigned)ih < 256u) & ((unsigned)iw < 256u);
        int s = d ^ (px & 7);                            // pre-swizzled source sub-seg
        const bfraw* g = ok ? in + ((nbase + (long)ih * 256 + iw) << 6) + s * 8 : zp;
        gl_lds16(g, &tile[(k * 256 + wv * 64) * 8]);
    }
    if (tid < 32) {
        int t = 2560 + tid;
        int px = t >> 3, d = t & 7;
        int pr = px / 18, pc = px - pr * 18;
        int ih = r0 - 1 + pr, iw = c0 - 1 + pc;
        bool ok = ((unsigned)ih < 256u) & ((unsigned)iw < 256u);
        int s = d ^ (px & 7);
        const bfraw* g = ok ? in + ((nbase + (long)ih * 256 + iw) << 6) + s * 8 : zp;
        gl_lds16(g, &tile[2560 * 8]);
    }
    __syncthreads();

    // ---- compute: 1 output px per thread ----
    const int pr_out = tid >> 4, pc_out = tid & 15;
    float a0 = bias[0], a1 = bias[1], a2 = bias[2];
#pragma unroll
    for (int kh = 0; kh < 3; ++kh) {
#pragma unroll
        for (int kw = 0; kw < 3; ++kw) {
            const int q = (pr_out + 2 - kh) * 18 + (pc_out + 2 - kw);
            const int q7 = q & 7;
            const float* w0 = wt + (kh * 3 + kw) * 192;
#pragma unroll
            for (int j = 0; j < 8; ++j) {               // channel block j (ch 8j..8j+7)
                uint4 u = *(const uint4*)&tile[(q * 8 + (j ^ q7)) * 8];
                const float* wd = w0 + j * 24;
                float v0 = bflo(u.x), v1 = bfhi(u.x);
                float v2 = bflo(u.y), v3 = bfhi(u.y);
                float v4 = bflo(u.z), v5 = bfhi(u.z);
                float v6 = bflo(u.w), v7 = bfhi(u.w);
                a0 = fmaf(v0, wd[0],  a0); a1 = fmaf(v0, wd[1],  a1); a2 = fmaf(v0, wd[2],  a2);
                a0 = fmaf(v1, wd[3],  a0); a1 = fmaf(v1, wd[4],  a1); a2 = fmaf(v1, wd[5],  a2);
                a0 = fmaf(v2, wd[6],  a0); a1 = fmaf(v2, wd[7],  a1); a2 = fmaf(v2, wd[8],  a2);
                a0 = fmaf(v3, wd[9],  a0); a1 = fmaf(v3, wd[10], a1); a2 = fmaf(v3, wd[11], a2);
                a0 = fmaf(v4, wd[12], a0); a1 = fmaf(v4, wd[13], a1); a2 = fmaf(v4, wd[14], a2);
                a0 = fmaf(v5, wd[15], a0); a1 = fmaf(v5, wd[16], a1); a2 = fmaf(v5, wd[17], a2);
                a0 = fmaf(v6, wd[18], a0); a1 = fmaf(v6, wd[19], a1); a2 = fmaf(v6, wd[20], a2);
                a0 = fmaf(v7, wd[21], a0); a1 = fmaf(v7, wd[22], a1); a2 = fmaf(v7, wd[23], a2);
            }
        }
    }

    const int oh = r0 + pr_out, ow = c0 + pc_out;
    const long sp = (long)n * 196608;
    const long hw = (long)oh * 256 + ow;
    out[sp + hw] = a0; out[sp + 65536 + hw] = a1; out[sp + 131072 + hw] = a2;
}

// ---------------------------------------------------------------------------
// VQ partial argmin: grid (512 row-blocks x 4 code-chunks). Block = 128 rows
// x 128 codes, K=256 via 8 ksteps of the R6-proven 2-barrier staged loop
// (18.6 KB LDS -> 4 blocks/CU). dist = ||e||^2 - 2*S; per-lane strict-< in
// ascending code order, 16-lane shuffle reduce, cross-half LDS merge, then
// ONE (val,key) partial per row to pb[chunk*65536 + pos]. No gather, no
// atomics here. Distances bit-identical to R7 (same k-slab mapping).
// ---------------------------------------------------------------------------
__global__ __launch_bounds__(256) void vqm_kernel(
    const bfraw* __restrict__ zeb, const bfraw* __restrict__ embB,
    const float* __restrict__ esq, float2* __restrict__ pb)
{
    __shared__ __align__(16) bfraw ldsA[128 * 32];
    __shared__ __align__(16) bfraw ldsB[128 * 32];
    __shared__ float sEsq[128];
    __shared__ float sVal[2][128];
    __shared__ int   sKey[2][128];
    const int tid = threadIdx.x, lane = tid & 63, wv = tid >> 6;
    const int wm = wv >> 1, wn = wv & 1;
    const int lrow = lane >> 2, lkof = (lane & 3) * 8;
    const int quad = lane >> 4, r16 = lane & 15;
    const int posBase = blockIdx.x * 128;
    const int codeBase = blockIdx.y * 128;

    if (tid < 128) sEsq[tid] = esq[codeBase + tid];

    const long baseA0 = (long)(posBase + wv * 16 + lrow) * 256 + lkof;
    const long baseA1 = baseA0 + 64 * 256;
    const long baseB0 = (long)(codeBase + wv * 16 + lrow) * 256 + lkof;
    const long baseB1 = baseB0 + 64 * 256;

    f32x4 acc[4][4];
#pragma unroll
    for (int i = 0; i < 4; ++i)
#pragma unroll
        for (int j = 0; j < 4; ++j) acc[i][j] = (f32x4)0.f;

    for (int k = 0; k < 8; ++k) {
        gl_lds16(zeb + baseA0 + k * 32, &ldsA[(wv * 16) * 32]);
        gl_lds16(zeb + baseA1 + k * 32, &ldsA[(64 + wv * 16) * 32]);
        gl_lds16(embB + baseB0 + k * 32, &ldsB[(wv * 16) * 32]);
        gl_lds16(embB + baseB1 + k * 32, &ldsB[(64 + wv * 16) * 32]);
        __syncthreads();
        s16x8 af[4], bf[4];
#pragma unroll
        for (int i = 0; i < 4; ++i)
            af[i] = *(const s16x8*)&ldsA[(wm * 64 + i * 16 + r16) * 32 + quad * 8];
#pragma unroll
        for (int j = 0; j < 4; ++j)
            bf[j] = *(const s16x8*)&ldsB[(wn * 64 + j * 16 + r16) * 32 + quad * 8];
#pragma unroll
        for (int i = 0; i < 4; ++i)
#pragma unroll
            for (int j = 0; j < 4; ++j)
                acc[i][j] = __builtin_amdgcn_mfma_f32_16x16x32_bf16(af[i], bf[j], acc[i][j], 0, 0, 0);
        __syncthreads();
    }

    // epilogue: dist + argmin. C row = i*16 + quad*4 + r (in wm half), col = r16.
#pragma unroll
    for (int i = 0; i < 4; ++i) {
#pragma unroll
        for (int r = 0; r < 4; ++r) {
            float v = 1e30f; int kk = 1 << 30;
#pragma unroll
            for (int j = 0; j < 4; ++j) {           // j ascending -> codes ascending
                int code = codeBase + wn * 64 + j * 16 + r16;
                float d = sEsq[wn * 64 + j * 16 + r16] - 2.f * acc[i][j][r];
                if (d < v) { v = d; kk = code; }    // strict < keeps first index
            }
#pragma unroll
            for (int m = 1; m < 16; m <<= 1) {
                float ov = __shfl_xor(v, m, 64);
                int   ok = __shfl_xor(kk, m, 64);
                if (ov < v || (ov == v && ok < kk)) { v = ov; kk = ok; }
            }
            if (r16 == 0) {
                int localRow = wm * 64 + i * 16 + quad * 4 + r;
                sVal[wn][localRow] = v;
                sKey[wn][localRow] = kk;
            }
        }
    }
    __syncthreads();
    // merge halves: one (val,key) partial per row for this code chunk
    if (tid < 128) {
        float v0 = sVal[0][tid]; int k0 = sKey[0][tid];
        float v1 = sVal[1][tid]; int k1 = sKey[1][tid];
        bool take1 = (v1 < v0) || (v1 == v0 && k1 < k0);
        float2 p; p.x = take1 ? v1 : v0;
        p.y = __int_as_float(take1 ? k1 : k0);
        pb[(long)blockIdx.y * 65536 + posBase + tid] = p;
    }
}

// ---------------------------------------------------------------------------
// VQ merge + gather: 2048 blocks x 32 px. Merge the 4 chunk partials
// (ascending chunk order + key tie-break -> global first-min), one hist
// atomic per px, then stream zq (fp32) + zqb (bf16) at full write BW.
// ---------------------------------------------------------------------------
__global__ __launch_bounds__(256) void vqg_kernel(
    const float2* __restrict__ pb, const float* __restrict__ emb,
    float* __restrict__ zq, bfraw* __restrict__ zqb, int* __restrict__ hist)
{
    __shared__ int sIdxL[32];
    const int tid = threadIdx.x;
    const int posBase = blockIdx.x * 32;
    if (tid < 32) {
        float bv = 1e30f; int bk = 1 << 30;
#pragma unroll
        for (int c = 0; c < 4; ++c) {
            float2 p = pb[(long)c * 65536 + posBase + tid];
            int k = __float_as_int(p.y);
            if (p.x < bv || (p.x == bv && k < bk)) { bv = p.x; bk = k; }
        }
        sIdxL[tid] = bk;
        atomicAdd(&hist[bk], 1);
    }
    __syncthreads();
    const float4* emb4 = (const float4*)emb;
    float4*  zq4  = (float4*)(zq + (long)posBase * 256);
    ushort4* zqb4 = (ushort4*)(zqb + (long)posBase * 256);
#pragma unroll
    for (int it = 0; it < 8; ++it) {
        int i2 = it * 256 + tid;
        int p = i2 >> 6, c = i2 & 63;
        float4 vv = emb4[(long)sIdxL[p] * 64 + c];
        zq4[i2] = vv;
        ushort4 u; u.x = f2bf(vv.x); u.y = f2bf(vv.y); u.z = f2bf(vv.z); u.w = f2bf(vv.w);
        zqb4[i2] = u;
    }
}

// --- perplexity
__global__ void ppl_kernel(const int* __restrict__ hist, float* __restrict__ outp) {
    __shared__ float red[512];
    int t = threadIdx.x;
    float p = (float)hist[t] * (1.0f / 65536.0f);
    red[t] = p * logf(p + 1e-10f);
    __syncthreads();
    for (int s = 256; s; s >>= 1) { if (t < s) red[t] += red[t + s]; __syncthreads(); }
    if (t == 0) *outp = expf(-red[0]);
}

// host: pack convT parity-class tap table (4 entries x 16 bits)
static unsigned long long packFor(int py, int px) {
    unsigned long long pk = 0; int s = 0;
    for (int kh = 0; kh < 4; ++kh) {
        if (((py + 1 - kh) & 1) != 0) continue;
        int dy = (py + 1 - kh) / 2;
        for (int kw = 0; kw < 4; ++kw) {
            if (((px + 1 - kw) & 1) != 0) continue;
            int dx = (px + 1 - kw) / 2;
            unsigned e = ((unsigned)(dy + 1) << 8) | ((unsigned)(dx + 1) << 4) | (unsigned)(kh * 4 + kw);
            pk |= (unsigned long long)e << (16 * s); ++s;
        }
    }
    return pk;
}

extern "C" void kernel_launch(void* const* d_in, const int* in_sizes, int n_in,
                              void* d_out, int out_size, void* d_ws, size_t ws_size,
                              hipStream_t stream) {
    const float* x       = (const float*)d_in[0];
    const float* w_enc1  = (const float*)d_in[1];
    const float* b_enc1  = (const float*)d_in[2];
    const float* w_enc2  = (const float*)d_in[3];
    const float* b_enc2  = (const float*)d_in[4];
    const float* w_prevq = (const float*)d_in[5];
    const float* b_prevq = (const float*)d_in[6];
    const float* emb     = (const float*)d_in[7];
    const float* w_post  = (const float*)d_in[8];
    const float* b_post  = (const float*)d_in[9];
    const float* w_dec1  = (const float*)d_in[10];
    const float* b_dec1  = (const float*)d_in[11];
    const float* w_dec2  = (const float*)d_in[12];
    const float* b_dec2  = (const float*)d_in[13];

    float* out = (float*)d_out;
    float* xr  = out;                     // 3,145,728
    float* ze  = out + 3145728;           // 16,777,216
    float* zq  = ze + 16777216;           // 16,777,216
    float* ppl = zq + 16777216;           // 1

    // ---- workspace carve (bytes) ----
    char* W = (char*)d_ws;
    float* wd2t = (float*)(W + 16384);      // dec2 fp32 [tap][ci][co]    7 KB
    float* esq  = (float*)(W + 24576);      // 2 KB
    int*   hist = (int*)(W + 28672);        // 2 KB
    bfraw* zp   = (bfraw*)(W + 32768);      // zero page, 256 B
    bfraw* w2b  = (bfraw*)(W + 560128);     // enc2  bf16 [co][16][64]   256 KB
    bfraw* w3b  = (bfraw*)(W + 822272);     // prevq bf16 [co][9][128]   576 KB
    bfraw* wpb  = (bfraw*)(W + 1412096);    // post  bf16 [co][16][256]  1 MB
    bfraw* wd1b = (bfraw*)(W + 2460672);    // dec1  bf16 [co][16][128]  256 KB
    bfraw* wb1  = (bfraw*)(W + 2722816);    // enc1  bf16 [co][64]        8 KB
    bfraw* embB = (bfraw*)(W + 2736128);    // emb   bf16 [512][256]    256 KB
    // bufX (128 MiB @ +4 MiB): sequential lifetimes
    //   a0 [0,33.5M) -> h2 [0,16.8M) -> zeb [16.8M,50.3M) -> zqb [50.3M,83.9M)
    //   -> ddec1 [0,134.2M). pb (2 MB) lives at bufX+0 during VQ (a0/h2 dead).
    char* bufX = W + 4194304;
    bfraw* a0    = (bfraw*)bufX;
    bfraw* h2    = (bfraw*)bufX;
    bfraw* zeb   = (bfraw*)(bufX + 16777216);
    bfraw* zqb   = (bfraw*)(bufX + 50331648);
    bfraw* ddec1 = (bfraw*)bufX;
    float2* pb   = (float2*)bufX;           // 4*65536*8 B = 2 MB (VQ partials)
    // bufY (67.1 MB): dpost
    bfraw* dpost = (bfraw*)(W + 138412032);
    bfraw* h1    = (bfraw*)ze;              // alias: h1 dies before prevq writes z_e

    // ---- weight transforms + precomputes ----
    wt_kernel<<<8, 256, 0, stream>>>(w_dec2, wd2t, 3, 64, 3, 3, 1);
    wb1_kernel<<<16, 256, 0, stream>>>(w_enc1, wb1);
    wtb_kernel<<<512, 256, 0, stream>>>(w_enc2, w2b, 128, 64, 4, 4, 0);
    wtb_kernel<<<1152, 256, 0, stream>>>(w_prevq, w3b, 256, 128, 3, 3, 0);
    wtb_kernel<<<2048, 256, 0, stream>>>(w_post, wpb, 128, 256, 4, 4, 1);
    wtb_kernel<<<512, 256, 0, stream>>>(w_dec1, wd1b, 64, 128, 4, 4, 1);
    wtb_kernel<<<512, 256, 0, stream>>>(emb, embB, 512, 256, 1, 1, 0);
    embsq_kernel<<<512, 64, 0, stream>>>(emb, esq);
    hipMemsetAsync(hist, 0, 512 * sizeof(int), stream);
    hipMemsetAsync(zp, 0, 256, stream);

    // ---- encoder ----
    xpack_kernel<<<1024, 256, 0, stream>>>(x, a0);
    igemm_kernel<256, 64, 4, 1, false, true, false, false><<<dim3(1024, 1), 256, 0, stream>>>(
        a0, wb1, b_enc1, h1, nullptr, zp, 512, 512, 64, 1, 1, 2, 9, 9, 64, 1, 0, 0, 0, 0ULL);
    igemm_kernel<128, 128, 2, 2, false, true, false, false><<<dim3(512, 1), 256, 0, stream>>>(
        h1, w2b, b_enc2, h2, nullptr, zp, 128, 128, 64, 2, 16, 32, 6, 6, 128, 4, 1, 0, 0, 0ULL);
    // prevq: dual output ze fp32 + zeb bf16
    igemm_kernel<128, 128, 2, 2, false, false, true, true><<<dim3(512, 2), 256, 0, stream>>>(
        h2, w3b, b_prevq, ze, zeb, zp, 64, 64, 128, 1, 9, 36, 6, 6, 256, 3, 1, 0, 0, 0ULL);

    // ---- VQ: partial argmin (512x4 blocks) -> merge+gather (2048 blocks) ----
    vqm_kernel<<<dim3(512, 4), 256, 0, stream>>>(zeb, embB, esq, pb);
    vqg_kernel<<<2048, 256, 0, stream>>>(pb, emb, zq, zqb, hist);
    ppl_kernel<<<1, 512, 0, stream>>>(hist, ppl);

    // ---- decoder ----
    for (int cls = 0; cls < 4; ++cls) {
        int py = cls >> 1, px = cls & 1;
        igemm_kernel<128, 128, 2, 2, true, false, false, false><<<dim3(512, 1), 256, 0, stream>>>(
            zqb, wpb, b_post, dpost, nullptr, zp, 64, 64, 256, 1, 16, 32, 6, 6, 128, 4, 1,
            py, px, packFor(py, px));
    }
    for (int cls = 0; cls < 4; ++cls) {
        int py = cls >> 1, px = cls & 1;
        igemm_kernel<256, 64, 4, 1, true, true, false, false><<<dim3(1024, 1), 256, 0, stream>>>(
            dpost, wd1b, b_dec1, ddec1, nullptr, zp, 128, 128, 128, 1, 16, 16, 7, 7, 64, 4, 1,
            py, px, packFor(py, px));
    }
    dec2_kernel<<<4096, 256, 0, stream>>>(ddec1, wd2t, b_dec2, xr, zp);
}

// Round 5
// 890.594 us; speedup vs baseline: 1.0650x; 1.0650x over previous
//
#include <hip/hip_runtime.h>
#include <stdint.h>

// ---------------------------------------------------------------------------
// VQ-VAE forward on MI355X. Round 9: dec2 -> MFMA. R8 dec2 was VALU-bound
// (VALUBusy 70%, MfmaUtil 0): 1728 scalar FMA/px + 576 extracts = matmul-
// shaped work off the matrix cores. R9 dec2m: same R6 swizzled 18x18x64 halo
// staging (proven), weights as zero-padded B[16][576] bf16 (co 0..2 real),
// col-swizzled in LDS; then 18 ksteps x (4 ds_read A-frag + 1 B-frag +
// 4 mfma_16x16x32_bf16) per wave with NO barriers after the single staging
// barrier. Fragment mapping cloned from the verified igemm. Epilogue: lanes
// r16<3 write the 3 fp32 NCHW planes. Rest identical to R8.
// ---------------------------------------------------------------------------

typedef unsigned short bfraw;
typedef __attribute__((ext_vector_type(8))) short s16x8;
typedef __attribute__((ext_vector_type(4))) float f32x4;

__device__ __forceinline__ float bflo(unsigned int u) {
    union { unsigned int i; float f; } v; v.i = u << 16; return v.f;
}
__device__ __forceinline__ float bfhi(unsigned int u) {
    union { unsigned int i; float f; } v; v.i = u & 0xFFFF0000u; return v.f;
}
__device__ __forceinline__ bfraw f2bf(float f) {
    union { float f; unsigned int i; } v; v.f = f;
    unsigned int r = v.i + 0x7FFFu + ((v.i >> 16) & 1u);   // RNE
    return (bfraw)(r >> 16);
}

// async 16B global->LDS. LDS dest: wave-uniform base + lane*16; global src per-lane.
__device__ __forceinline__ void gl_lds16(const void* g, void* l) {
    auto gp = reinterpret_cast<const __attribute__((address_space(1))) unsigned int*>(
        reinterpret_cast<uintptr_t>(g));
    auto lp = reinterpret_cast<__attribute__((address_space(3))) unsigned int*>(
        reinterpret_cast<uintptr_t>(l));
    __builtin_amdgcn_global_load_lds(gp, lp, 16, 0, 0);
}

// --- weight transform (bf16, [co][tap][ci]) for MFMA convs (B as [n][k]);
//     with KH=KW=1 also converts emb[512][256] to bf16 B layout.
__global__ void wtb_kernel(const float* __restrict__ w, bfraw* __restrict__ wt,
                           int Cout, int Cin, int KH, int KW, int transposed) {
    int n = Cout * Cin * KH * KW;
    int NT = KH * KW;
    for (int i = blockIdx.x * blockDim.x + threadIdx.x; i < n; i += gridDim.x * blockDim.x) {
        int ci = i % Cin; int t = i / Cin;
        int tap = t % NT; int co = t / NT;
        int kh = tap / KW, kw = tap % KW;
        float v = transposed ? w[(((long)ci * Cout + co) * KH + kh) * KW + kw]
                             : w[(((long)co * Cin + ci) * KH + kh) * KW + kw];
        wt[i] = f2bf(v);
    }
}

// --- dec2 weight pack: wb2[16][576] bf16, B[co][tap*64+ci]; rows 3..15 zero.
//     convT k3 p1 == conv with wf[co][ci][kh'][kw'] = w[ci][co][2-kh'][2-kw'].
__global__ void wb2_kernel(const float* __restrict__ w, bfraw* __restrict__ wt) {
    int i = blockIdx.x * 256 + threadIdx.x;   // 9216 = 16*576
    if (i >= 9216) return;
    int ci = i & 63; int t = i >> 6;          // t = co*9 + tap
    int tap = t % 9, co = t / 9;
    bfraw v = 0;
    if (co < 3) {
        int kh = 2 - tap / 3, kw = 2 - tap % 3;
        v = f2bf(w[(((long)ci * 3 + co) * 3 + kh) * 3 + kw]);
    }
    wt[(long)co * 576 + tap * 64 + ci] = v;
}

// --- enc1 weight pack: wb1[co][k64], k=(kh*4+kw)*3+ci (48 real, 16 zero)
__global__ void wb1_kernel(const float* __restrict__ w, bfraw* __restrict__ wt) {
    int i = blockIdx.x * 256 + threadIdx.x;
    if (i >= 4096) return;
    int k = i & 63, co = i >> 6;
    bfraw v = 0;
    if (k < 48) {
        int ci = k % 3, tap = k / 3, kh = tap >> 2, kw = tap & 3;
        v = f2bf(w[(((long)co * 3 + ci) * 4 + kh) * 4 + kw]);
    }
    wt[(long)co * 64 + k] = v;
}

// --- enc1 im2col: x NCHW fp32 -> A0[pos][64] bf16 (48 patch vals + 16 zeros)
__global__ __launch_bounds__(256) void xpack_kernel(const float* __restrict__ x,
                                                    bfraw* __restrict__ a0) {
    int pos = blockIdx.x * 256 + threadIdx.x;        // 262144
    int ow = pos & 127, oh = (pos >> 7) & 127, n = pos >> 14;
    __align__(16) bfraw v[64];
#pragma unroll
    for (int i = 0; i < 64; ++i) v[i] = 0;
#pragma unroll
    for (int kh = 0; kh < 4; ++kh) {
        int ih = 2 * oh - 1 + kh; if ((unsigned)ih >= 256u) continue;
#pragma unroll
        for (int kw = 0; kw < 4; ++kw) {
            int iw = 2 * ow - 1 + kw; if ((unsigned)iw >= 256u) continue;
#pragma unroll
            for (int ci = 0; ci < 3; ++ci)
                v[(kh * 4 + kw) * 3 + ci] =
                    f2bf(x[(((long)n * 3 + ci) * 256 + ih) * 256 + iw]);
        }
    }
    uint4* dst = (uint4*)(a0 + (long)pos * 64);
    const uint4* src = (const uint4*)v;
#pragma unroll
    for (int i = 0; i < 8; ++i) dst[i] = src[i];
}

// --- emb row norms
__global__ void embsq_kernel(const float* __restrict__ emb, float* __restrict__ esq) {
    int k = blockIdx.x, lane = threadIdx.x;
    float s = 0.f;
    for (int d = lane; d < 256; d += 64) { float v = emb[k * 256 + d]; s += v * v; }
    for (int o = 32; o; o >>= 1) s += __shfl_down(s, o, 64);
    if (lane == 0) esq[k] = s;
}

// ---------------------------------------------------------------------------
// MFMA implicit GEMM. C[MxN] = A[MxK]*B[KxN].
// ---------------------------------------------------------------------------
template<int BM, int BN, int WM, int WN, bool TR, bool RELU, bool OUTF32, bool DUALB>
__global__ __launch_bounds__(256) void igemm_kernel(
    const bfraw* __restrict__ in, const bfraw* __restrict__ wt,
    const float* __restrict__ bias, void* __restrict__ outv,
    bfraw* __restrict__ outb, const bfraw* __restrict__ zp,
    int Hin, int Win, int Cin, int sf, int NTW, int Ksteps,
    int lw, int lh, int N, int KW, int pad, int py, int px,
    unsigned long long pack)
{
    constexpr int APASS = BM / 64, BPASS = BN / 64;
    __shared__ __align__(16) bfraw ldsA[BM * 32];
    __shared__ __align__(16) bfraw ldsB[BN * 32];
    const int tid = threadIdx.x, lane = tid & 63, wv = tid >> 6;
    const int wm = wv / WN, wn = wv % WN;
    const int lrow = lane >> 2, lkof = (lane & 3) * 8;
    const int blockM = blockIdx.x, n0 = blockIdx.y * BN;
    const int Wm1 = (1 << lw) - 1, Hm1 = (1 << lh) - 1;

    long baseA[APASS]; int ihb[APASS], iwb[APASS];
#pragma unroll
    for (int p = 0; p < APASS; ++p) {
        int m = p * 64 + wv * 16 + lrow;
        int pos = blockM * BM + m;
        int ow = pos & Wm1; int t = pos >> lw;
        int oh = t & Hm1;   int nb = t >> lh;
        ihb[p] = oh * sf; iwb[p] = ow * sf;
        baseA[p] = ((long)(nb * Hin + ihb[p]) * Win + iwb[p]) * (long)Cin + lkof;
    }
    long baseB[BPASS];
#pragma unroll
    for (int p = 0; p < BPASS; ++p) {
        int nl = p * 64 + wv * 16 + lrow;
        baseB[p] = (long)(n0 + nl) * ((long)NTW * Cin) + lkof;
    }

    f32x4 acc[4][4];
#pragma unroll
    for (int i = 0; i < 4; ++i)
#pragma unroll
        for (int j = 0; j < 4; ++j) acc[i][j] = (f32x4)0.f;

    int ci0 = 0, tslot = 0, dy, dx, wk;
    if (TR) {
        unsigned e = (unsigned)pack & 0xFFFFu;
        dy = (int)((e >> 8) & 3) - 1; dx = (int)((e >> 4) & 3) - 1; wk = (int)(e & 15u);
    } else { dy = -pad; dx = -pad; wk = 0; }

    const int quad = lane >> 4, r16 = lane & 15;

    for (int ks = 0; ks < Ksteps; ++ks) {
        long offA = ((long)(dy * Win + dx)) * Cin + ci0;
        long offB = (long)wk * Cin + ci0;
#pragma unroll
        for (int p = 0; p < APASS; ++p) {
            int ih = ihb[p] + dy, iw = iwb[p] + dx;
            bool ok = ((unsigned)ih < (unsigned)Hin) & ((unsigned)iw < (unsigned)Win);
            const bfraw* g = ok ? (in + baseA[p] + offA) : (zp + lkof);
            gl_lds16(g, &ldsA[(p * 64 + wv * 16) * 32]);
        }
#pragma unroll
        for (int p = 0; p < BPASS; ++p)
            gl_lds16(wt + baseB[p] + offB, &ldsB[(p * 64 + wv * 16) * 32]);
        __syncthreads();
        s16x8 af[4], bf[4];
#pragma unroll
        for (int i = 0; i < 4; ++i)
            af[i] = *(const s16x8*)&ldsA[(wm * 64 + i * 16 + r16) * 32 + quad * 8];
#pragma unroll
        for (int j = 0; j < 4; ++j)
            bf[j] = *(const s16x8*)&ldsB[(wn * 64 + j * 16 + r16) * 32 + quad * 8];
#pragma unroll
        for (int i = 0; i < 4; ++i)
#pragma unroll
            for (int j = 0; j < 4; ++j)
                acc[i][j] = __builtin_amdgcn_mfma_f32_16x16x32_bf16(af[i], bf[j], acc[i][j], 0, 0, 0);
        __syncthreads();
        ci0 += 32;
        if (ci0 == Cin) {
            ci0 = 0; ++tslot;
            if (TR) {
                unsigned e = (unsigned)(pack >> (tslot * 16)) & 0xFFFFu;
                dy = (int)((e >> 8) & 3) - 1; dx = (int)((e >> 4) & 3) - 1; wk = (int)(e & 15u);
            } else { ++wk; ++dx; if (dx == KW - pad) { dx = -pad; ++dy; } }
        }
    }

#pragma unroll
    for (int j = 0; j < 4; ++j) {
        int col = wn * 64 + j * 16 + r16; int ng = n0 + col;
        float bv = bias[ng];
#pragma unroll
        for (int i = 0; i < 4; ++i) {
            int mb = wm * 64 + i * 16 + quad * 4;
#pragma unroll
            for (int r = 0; r < 4; ++r) {
                int pos2 = blockM * BM + mb + r;
                long oaddr;
                if (TR) {
                    int ow2 = pos2 & Wm1; int t = pos2 >> lw;
                    int oh2 = t & Hm1;    int nb = t >> lh;
                    int oh = 2 * oh2 + py, ow = 2 * ow2 + px;
                    oaddr = ((long)(((nb << (lh + 1)) + oh) << (lw + 1)) + ow) * N + ng;
                } else {
                    oaddr = (long)pos2 * N + ng;
                }
                float v = acc[i][j][r] + bv;
                if (RELU) v = fmaxf(v, 0.f);
                if (OUTF32) {
                    ((float*)outv)[oaddr] = v;
                    if (DUALB) outb[oaddr] = f2bf(v);
                } else {
                    ((bfraw*)outv)[oaddr] = f2bf(v);
                }
            }
        }
    }
}

// ---------------------------------------------------------------------------
// dec2m: convT k3 s1 p1, 64->3ch via MFMA. Block = 16x16 output tile (grid
// 4096), 4 waves. Halo 18x18x64 staged once (px&7 sub-slot swizzle, as R6
// dec2). B = wb2[16][576] staged once, col&7 swizzled. Then 18 ksteps
// (tap, ci-half) x (4 A ds_read_b128 + 1 B read + 4 mfma_16x16x32_bf16)
// per wave, no barriers. A-frag: row r16 -> px (wv*4+i, r16); k = quad*8.
// C: row quad*4+r, col r16 = co. Lanes r16<3 write fp32 NCHW planes + bias.
// ---------------------------------------------------------------------------
__global__ __launch_bounds__(256) void dec2m_kernel(
    const bfraw* __restrict__ in, const bfraw* __restrict__ wb2,
    const float* __restrict__ bias, float* __restrict__ out,
    const bfraw* __restrict__ zp) {
    __shared__ __align__(16) bfraw tile[18 * 18 * 64];   // 41,472 B
    __shared__ __align__(16) bfraw ldsB[16 * 576];       // 18,432 B
    const int tid = threadIdx.x;
    const int b = blockIdx.x;
    const int n = b >> 8, t8 = b & 255;
    const int r0 = (t8 >> 4) * 16, c0 = (t8 & 15) * 16;
    const int wv = tid >> 6, lane = tid & 63;
    const int quad = lane >> 4, r16 = lane & 15;
    const long nbase = (long)n * 65536;

    // ---- stage halo: 2592 segs of 16B (identical to R6 dec2) ----
#pragma unroll
    for (int k = 0; k < 10; ++k) {
        int t = k * 256 + tid;
        int px = t >> 3, d = t & 7;
        int pr = px / 18, pc = px - pr * 18;
        int ih = r0 - 1 + pr, iw = c0 - 1 + pc;
        bool ok = ((unsigned)ih < 256u) & ((unsigned)iw < 256u);
        int s = d ^ (px & 7);                            // pre-swizzled source sub-seg
        const bfraw* g = ok ? in + ((nbase + (long)ih * 256 + iw) << 6) + s * 8 : zp;
        gl_lds16(g, &tile[(k * 256 + wv * 64) * 8]);
    }
    if (tid < 32) {
        int t = 2560 + tid;
        int px = t >> 3, d = t & 7;
        int pr = px / 18, pc = px - pr * 18;
        int ih = r0 - 1 + pr, iw = c0 - 1 + pc;
        bool ok = ((unsigned)ih < 256u) & ((unsigned)iw < 256u);
        int s = d ^ (px & 7);
        const bfraw* g = ok ? in + ((nbase + (long)ih * 256 + iw) << 6) + s * 8 : zp;
        gl_lds16(g, &tile[2560 * 8]);
    }
    // ---- stage B: 1152 segs of 16B; LDS slot (c,s) <- global seg s^(c&7) ----
#pragma unroll
    for (int k = 0; k < 4; ++k) {
        int t = k * 256 + tid;
        int c = t / 72, s = t - c * 72;
        gl_lds16(wb2 + (long)c * 576 + ((s ^ (c & 7)) << 3), &ldsB[(k * 256 + wv * 64) * 8]);
    }
    if (tid < 128) {
        int t = 1024 + tid;
        int c = t / 72, s = t - c * 72;
        gl_lds16(wb2 + (long)c * 576 + ((s ^ (c & 7)) << 3), &ldsB[(1024 + wv * 64) * 8]);
    }
    __syncthreads();   // drains vmcnt: halo + B resident

    f32x4 acc[4];
#pragma unroll
    for (int i = 0; i < 4; ++i) acc[i] = (f32x4)0.f;

    int qb[4];
#pragma unroll
    for (int i = 0; i < 4; ++i) qb[i] = (wv * 4 + i + 1) * 18 + (r16 + 1);

#pragma unroll
    for (int ks = 0; ks < 18; ++ks) {
        const int tap = ks >> 1, h = ks & 1;
        const int dy = tap / 3 - 1, dx = tap % 3 - 1;
        s16x8 bfr = *(const s16x8*)&ldsB[r16 * 576 + (((ks * 4 + quad) ^ (r16 & 7)) << 3)];
        s16x8 afr[4];
#pragma unroll
        for (int i = 0; i < 4; ++i) {
            int q = qb[i] + dy * 18 + dx;
            afr[i] = *(const s16x8*)&tile[(q << 6) + ((((h << 2) + quad) ^ (q & 7)) << 3)];
        }
#pragma unroll
        for (int i = 0; i < 4; ++i)
            acc[i] = __builtin_amdgcn_mfma_f32_16x16x32_bf16(afr[i], bfr, acc[i], 0, 0, 0);
    }

    // ---- epilogue: col r16 = co (0..2 real); row = quad*4 + r ----
    if (r16 < 3) {
        float bv = bias[r16];
        float* plane = out + (((long)(n * 3 + r16)) << 16);
#pragma unroll
        for (int i = 0; i < 4; ++i) {
            int oh = r0 + wv * 4 + i;
#pragma unroll
            for (int r = 0; r < 4; ++r) {
                int ow = c0 + quad * 4 + r;
                plane[((long)oh << 8) + ow] = acc[i][r] + bv;
            }
        }
    }
}

// ---------------------------------------------------------------------------
// VQ partial argmin: grid (512 row-blocks x 4 code-chunks). Block = 128 rows
// x 128 codes, K=256 via 8 ksteps of the R6-proven 2-barrier staged loop
// (18.6 KB LDS -> 4 blocks/CU). dist = ||e||^2 - 2*S; per-lane strict-< in
// ascending code order, 16-lane shuffle reduce, cross-half LDS merge, then
// ONE (val,key) partial per row to pb[chunk*65536 + pos].
// ---------------------------------------------------------------------------
__global__ __launch_bounds__(256) void vqm_kernel(
    const bfraw* __restrict__ zeb, const bfraw* __restrict__ embB,
    const float* __restrict__ esq, float2* __restrict__ pb)
{
    __shared__ __align__(16) bfraw ldsA[128 * 32];
    __shared__ __align__(16) bfraw ldsB[128 * 32];
    __shared__ float sEsq[128];
    __shared__ float sVal[2][128];
    __shared__ int   sKey[2][128];
    const int tid = threadIdx.x, lane = tid & 63, wv = tid >> 6;
    const int wm = wv >> 1, wn = wv & 1;
    const int lrow = lane >> 2, lkof = (lane & 3) * 8;
    const int quad = lane >> 4, r16 = lane & 15;
    const int posBase = blockIdx.x * 128;
    const int codeBase = blockIdx.y * 128;

    if (tid < 128) sEsq[tid] = esq[codeBase + tid];

    const long baseA0 = (long)(posBase + wv * 16 + lrow) * 256 + lkof;
    const long baseA1 = baseA0 + 64 * 256;
    const long baseB0 = (long)(codeBase + wv * 16 + lrow) * 256 + lkof;
    const long baseB1 = baseB0 + 64 * 256;

    f32x4 acc[4][4];
#pragma unroll
    for (int i = 0; i < 4; ++i)
#pragma unroll
        for (int j = 0; j < 4; ++j) acc[i][j] = (f32x4)0.f;

    for (int k = 0; k < 8; ++k) {
        gl_lds16(zeb + baseA0 + k * 32, &ldsA[(wv * 16) * 32]);
        gl_lds16(zeb + baseA1 + k * 32, &ldsA[(64 + wv * 16) * 32]);
        gl_lds16(embB + baseB0 + k * 32, &ldsB[(wv * 16) * 32]);
        gl_lds16(embB + baseB1 + k * 32, &ldsB[(64 + wv * 16) * 32]);
        __syncthreads();
        s16x8 af[4], bf[4];
#pragma unroll
        for (int i = 0; i < 4; ++i)
            af[i] = *(const s16x8*)&ldsA[(wm * 64 + i * 16 + r16) * 32 + quad * 8];
#pragma unroll
        for (int j = 0; j < 4; ++j)
            bf[j] = *(const s16x8*)&ldsB[(wn * 64 + j * 16 + r16) * 32 + quad * 8];
#pragma unroll
        for (int i = 0; i < 4; ++i)
#pragma unroll
            for (int j = 0; j < 4; ++j)
                acc[i][j] = __builtin_amdgcn_mfma_f32_16x16x32_bf16(af[i], bf[j], acc[i][j], 0, 0, 0);
        __syncthreads();
    }

    // epilogue: dist + argmin. C row = i*16 + quad*4 + r (in wm half), col = r16.
#pragma unroll
    for (int i = 0; i < 4; ++i) {
#pragma unroll
        for (int r = 0; r < 4; ++r) {
            float v = 1e30f; int kk = 1 << 30;
#pragma unroll
            for (int j = 0; j < 4; ++j) {           // j ascending -> codes ascending
                int code = codeBase + wn * 64 + j * 16 + r16;
                float d = sEsq[wn * 64 + j * 16 + r16] - 2.f * acc[i][j][r];
                if (d < v) { v = d; kk = code; }    // strict < keeps first index
            }
#pragma unroll
            for (int m = 1; m < 16; m <<= 1) {
                float ov = __shfl_xor(v, m, 64);
                int   ok = __shfl_xor(kk, m, 64);
                if (ov < v || (ov == v && ok < kk)) { v = ov; kk = ok; }
            }
            if (r16 == 0) {
                int localRow = wm * 64 + i * 16 + quad * 4 + r;
                sVal[wn][localRow] = v;
                sKey[wn][localRow] = kk;
            }
        }
    }
    __syncthreads();
    // merge halves: one (val,key) partial per row for this code chunk
    if (tid < 128) {
        float v0 = sVal[0][tid]; int k0 = sKey[0][tid];
        float v1 = sVal[1][tid]; int k1 = sKey[1][tid];
        bool take1 = (v1 < v0) || (v1 == v0 && k1 < k0);
        float2 p; p.x = take1 ? v1 : v0;
        p.y = __int_as_float(take1 ? k1 : k0);
        pb[(long)blockIdx.y * 65536 + posBase + tid] = p;
    }
}

// ---------------------------------------------------------------------------
// VQ merge + gather: 2048 blocks x 32 px. Merge the 4 chunk partials
// (ascending chunk order + key tie-break -> global first-min), one hist
// atomic per px, then stream zq (fp32) + zqb (bf16) at full write BW.
// ---------------------------------------------------------------------------
__global__ __launch_bounds__(256) void vqg_kernel(
    const float2* __restrict__ pb, const float* __restrict__ emb,
    float* __restrict__ zq, bfraw* __restrict__ zqb, int* __restrict__ hist)
{
    __shared__ int sIdxL[32];
    const int tid = threadIdx.x;
    const int posBase = blockIdx.x * 32;
    if (tid < 32) {
        float bv = 1e30f; int bk = 1 << 30;
#pragma unroll
        for (int c = 0; c < 4; ++c) {
            float2 p = pb[(long)c * 65536 + posBase + tid];
            int k = __float_as_int(p.y);
            if (p.x < bv || (p.x == bv && k < bk)) { bv = p.x; bk = k; }
        }
        sIdxL[tid] = bk;
        atomicAdd(&hist[bk], 1);
    }
    __syncthreads();
    const float4* emb4 = (const float4*)emb;
    float4*  zq4  = (float4*)(zq + (long)posBase * 256);
    ushort4* zqb4 = (ushort4*)(zqb + (long)posBase * 256);
#pragma unroll
    for (int it = 0; it < 8; ++it) {
        int i2 = it * 256 + tid;
        int p = i2 >> 6, c = i2 & 63;
        float4 vv = emb4[(long)sIdxL[p] * 64 + c];
        zq4[i2] = vv;
        ushort4 u; u.x = f2bf(vv.x); u.y = f2bf(vv.y); u.z = f2bf(vv.z); u.w = f2bf(vv.w);
        zqb4[i2] = u;
    }
}

// --- perplexity
__global__ void ppl_kernel(const int* __restrict__ hist, float* __restrict__ outp) {
    __shared__ float red[512];
    int t = threadIdx.x;
    float p = (float)hist[t] * (1.0f / 65536.0f);
    red[t] = p * logf(p + 1e-10f);
    __syncthreads();
    for (int s = 256; s; s >>= 1) { if (t < s) red[t] += red[t + s]; __syncthreads(); }
    if (t == 0) *outp = expf(-red[0]);
}

// host: pack convT parity-class tap table (4 entries x 16 bits)
static unsigned long long packFor(int py, int px) {
    unsigned long long pk = 0; int s = 0;
    for (int kh = 0; kh < 4; ++kh) {
        if (((py + 1 - kh) & 1) != 0) continue;
        int dy = (py + 1 - kh) / 2;
        for (int kw = 0; kw < 4; ++kw) {
            if (((px + 1 - kw) & 1) != 0) continue;
            int dx = (px + 1 - kw) / 2;
            unsigned e = ((unsigned)(dy + 1) << 8) | ((unsigned)(dx + 1) << 4) | (unsigned)(kh * 4 + kw);
            pk |= (unsigned long long)e << (16 * s); ++s;
        }
    }
    return pk;
}

extern "C" void kernel_launch(void* const* d_in, const int* in_sizes, int n_in,
                              void* d_out, int out_size, void* d_ws, size_t ws_size,
                              hipStream_t stream) {
    const float* x       = (const float*)d_in[0];
    const float* w_enc1  = (const float*)d_in[1];
    const float* b_enc1  = (const float*)d_in[2];
    const float* w_enc2  = (const float*)d_in[3];
    const float* b_enc2  = (const float*)d_in[4];
    const float* w_prevq = (const float*)d_in[5];
    const float* b_prevq = (const float*)d_in[6];
    const float* emb     = (const float*)d_in[7];
    const float* w_post  = (const float*)d_in[8];
    const float* b_post  = (const float*)d_in[9];
    const float* w_dec1  = (const float*)d_in[10];
    const float* b_dec1  = (const float*)d_in[11];
    const float* w_dec2  = (const float*)d_in[12];
    const float* b_dec2  = (const float*)d_in[13];

    float* out = (float*)d_out;
    float* xr  = out;                     // 3,145,728
    float* ze  = out + 3145728;           // 16,777,216
    float* zq  = ze + 16777216;           // 16,777,216
    float* ppl = zq + 16777216;           // 1

    // ---- workspace carve (bytes) ----
    char* W = (char*)d_ws;
    float* esq  = (float*)(W + 24576);      // 2 KB
    int*   hist = (int*)(W + 28672);        // 2 KB
    bfraw* zp   = (bfraw*)(W + 32768);      // zero page, 256 B
    bfraw* wb2  = (bfraw*)(W + 262144);     // dec2 bf16 [16][576]       18.4 KB
    bfraw* w2b  = (bfraw*)(W + 560128);     // enc2  bf16 [co][16][64]   256 KB
    bfraw* w3b  = (bfraw*)(W + 822272);     // prevq bf16 [co][9][128]   576 KB
    bfraw* wpb  = (bfraw*)(W + 1412096);    // post  bf16 [co][16][256]  1 MB
    bfraw* wd1b = (bfraw*)(W + 2460672);    // dec1  bf16 [co][16][128]  256 KB
    bfraw* wb1  = (bfraw*)(W + 2722816);    // enc1  bf16 [co][64]        8 KB
    bfraw* embB = (bfraw*)(W + 2736128);    // emb   bf16 [512][256]    256 KB
    // bufX (128 MiB @ +4 MiB): sequential lifetimes
    //   a0 [0,33.5M) -> h2 [0,16.8M) -> zeb [16.8M,50.3M) -> zqb [50.3M,83.9M)
    //   -> ddec1 [0,134.2M). pb (2 MB) lives at bufX+0 during VQ (a0/h2 dead).
    char* bufX = W + 4194304;
    bfraw* a0    = (bfraw*)bufX;
    bfraw* h2    = (bfraw*)bufX;
    bfraw* zeb   = (bfraw*)(bufX + 16777216);
    bfraw* zqb   = (bfraw*)(bufX + 50331648);
    bfraw* ddec1 = (bfraw*)bufX;
    float2* pb   = (float2*)bufX;           // 4*65536*8 B = 2 MB (VQ partials)
    // bufY (67.1 MB): dpost
    bfraw* dpost = (bfraw*)(W + 138412032);
    bfraw* h1    = (bfraw*)ze;              // alias: h1 dies before prevq writes z_e

    // ---- weight transforms + precomputes ----
    wb2_kernel<<<36, 256, 0, stream>>>(w_dec2, wb2);
    wb1_kernel<<<16, 256, 0, stream>>>(w_enc1, wb1);
    wtb_kernel<<<512, 256, 0, stream>>>(w_enc2, w2b, 128, 64, 4, 4, 0);
    wtb_kernel<<<1152, 256, 0, stream>>>(w_prevq, w3b, 256, 128, 3, 3, 0);
    wtb_kernel<<<2048, 256, 0, stream>>>(w_post, wpb, 128, 256, 4, 4, 1);
    wtb_kernel<<<512, 256, 0, stream>>>(w_dec1, wd1b, 64, 128, 4, 4, 1);
    wtb_kernel<<<512, 256, 0, stream>>>(emb, embB, 512, 256, 1, 1, 0);
    embsq_kernel<<<512, 64, 0, stream>>>(emb, esq);
    hipMemsetAsync(hist, 0, 512 * sizeof(int), stream);
    hipMemsetAsync(zp, 0, 256, stream);

    // ---- encoder ----
    xpack_kernel<<<1024, 256, 0, stream>>>(x, a0);
    igemm_kernel<256, 64, 4, 1, false, true, false, false><<<dim3(1024, 1), 256, 0, stream>>>(
        a0, wb1, b_enc1, h1, nullptr, zp, 512, 512, 64, 1, 1, 2, 9, 9, 64, 1, 0, 0, 0, 0ULL);
    igemm_kernel<128, 128, 2, 2, false, true, false, false><<<dim3(512, 1), 256, 0, stream>>>(
        h1, w2b, b_enc2, h2, nullptr, zp, 128, 128, 64, 2, 16, 32, 6, 6, 128, 4, 1, 0, 0, 0ULL);
    // prevq: dual output ze fp32 + zeb bf16
    igemm_kernel<128, 128, 2, 2, false, false, true, true><<<dim3(512, 2), 256, 0, stream>>>(
        h2, w3b, b_prevq, ze, zeb, zp, 64, 64, 128, 1, 9, 36, 6, 6, 256, 3, 1, 0, 0, 0ULL);

    // ---- VQ: partial argmin (512x4 blocks) -> merge+gather (2048 blocks) ----
    vqm_kernel<<<dim3(512, 4), 256, 0, stream>>>(zeb, embB, esq, pb);
    vqg_kernel<<<2048, 256, 0, stream>>>(pb, emb, zq, zqb, hist);
    ppl_kernel<<<1, 512, 0, stream>>>(hist, ppl);

    // ---- decoder ----
    for (int cls = 0; cls < 4; ++cls) {
        int py = cls >> 1, px = cls & 1;
        igemm_kernel<128, 128, 2, 2, true, false, false, false><<<dim3(512, 1), 256, 0, stream>>>(
            zqb, wpb, b_post, dpost, nullptr, zp, 64, 64, 256, 1, 16, 32, 6, 6, 128, 4, 1,
            py, px, packFor(py, px));
    }
    for (int cls = 0; cls < 4; ++cls) {
        int py = cls >> 1, px = cls & 1;
        igemm_kernel<256, 64, 4, 1, true, true, false, false><<<dim3(1024, 1), 256, 0, stream>>>(
            dpost, wd1b, b_dec1, ddec1, nullptr, zp, 128, 128, 128, 1, 16, 16, 7, 7, 64, 4, 1,
            py, px, packFor(py, px));
    }
    dec2m_kernel<<<4096, 256, 0, stream>>>(ddec1, wb2, b_dec2, xr, zp);
}

// Round 6
// 837.401 us; speedup vs baseline: 1.1327x; 1.0635x over previous
//
#include <hip/hip_runtime.h>
#include <stdint.h>

// ---------------------------------------------------------------------------
// VQ-VAE forward on MI355X. Round 10: igemm 2-phase pipeline. Budget math
// shows ~760us of the 890 is the igemm family at ~260 TF effective; its
// K-loop was the m196 "1-phase" shape (stage -> barrier/drain -> compute ->
// barrier, zero intra-wave overlap). R10: double-buffered LDS, STAGE(t+1)
// issued BEFORE compute(t), ONE barrier per K-step whose vmcnt(0) drain
// lands after the ds_read+MFMA phase (T3-minimum recipe, +28-41% in m196).
// LDS 2x (128^2 -> 32KB, 256x64 -> 40KB, both >=4 blocks/CU). Advance is
// now guarded (no pack>>64 on the last step). vqm/dec2m/dec2 unchanged.
// ---------------------------------------------------------------------------

typedef unsigned short bfraw;
typedef __attribute__((ext_vector_type(8))) short s16x8;
typedef __attribute__((ext_vector_type(4))) float f32x4;

__device__ __forceinline__ float bflo(unsigned int u) {
    union { unsigned int i; float f; } v; v.i = u << 16; return v.f;
}
__device__ __forceinline__ float bfhi(unsigned int u) {
    union { unsigned int i; float f; } v; v.i = u & 0xFFFF0000u; return v.f;
}
__device__ __forceinline__ bfraw f2bf(float f) {
    union { float f; unsigned int i; } v; v.f = f;
    unsigned int r = v.i + 0x7FFFu + ((v.i >> 16) & 1u);   // RNE
    return (bfraw)(r >> 16);
}

// async 16B global->LDS. LDS dest: wave-uniform base + lane*16; global src per-lane.
__device__ __forceinline__ void gl_lds16(const void* g, void* l) {
    auto gp = reinterpret_cast<const __attribute__((address_space(1))) unsigned int*>(
        reinterpret_cast<uintptr_t>(g));
    auto lp = reinterpret_cast<__attribute__((address_space(3))) unsigned int*>(
        reinterpret_cast<uintptr_t>(l));
    __builtin_amdgcn_global_load_lds(gp, lp, 16, 0, 0);
}

// --- weight transform (bf16, [co][tap][ci]) for MFMA convs (B as [n][k]);
//     with KH=KW=1 also converts emb[512][256] to bf16 B layout.
__global__ void wtb_kernel(const float* __restrict__ w, bfraw* __restrict__ wt,
                           int Cout, int Cin, int KH, int KW, int transposed) {
    int n = Cout * Cin * KH * KW;
    int NT = KH * KW;
    for (int i = blockIdx.x * blockDim.x + threadIdx.x; i < n; i += gridDim.x * blockDim.x) {
        int ci = i % Cin; int t = i / Cin;
        int tap = t % NT; int co = t / NT;
        int kh = tap / KW, kw = tap % KW;
        float v = transposed ? w[(((long)ci * Cout + co) * KH + kh) * KW + kw]
                             : w[(((long)co * Cin + ci) * KH + kh) * KW + kw];
        wt[i] = f2bf(v);
    }
}

// --- dec2 weight pack: wb2[16][576] bf16, B[co][tap*64+ci]; rows 3..15 zero.
//     convT k3 p1 == conv with wf[co][ci][kh'][kw'] = w[ci][co][2-kh'][2-kw'].
__global__ void wb2_kernel(const float* __restrict__ w, bfraw* __restrict__ wt) {
    int i = blockIdx.x * 256 + threadIdx.x;   // 9216 = 16*576
    if (i >= 9216) return;
    int ci = i & 63; int t = i >> 6;          // t = co*9 + tap
    int tap = t % 9, co = t / 9;
    bfraw v = 0;
    if (co < 3) {
        int kh = 2 - tap / 3, kw = 2 - tap % 3;
        v = f2bf(w[(((long)ci * 3 + co) * 3 + kh) * 3 + kw]);
    }
    wt[(long)co * 576 + tap * 64 + ci] = v;
}

// --- enc1 weight pack: wb1[co][k64], k=(kh*4+kw)*3+ci (48 real, 16 zero)
__global__ void wb1_kernel(const float* __restrict__ w, bfraw* __restrict__ wt) {
    int i = blockIdx.x * 256 + threadIdx.x;
    if (i >= 4096) return;
    int k = i & 63, co = i >> 6;
    bfraw v = 0;
    if (k < 48) {
        int ci = k % 3, tap = k / 3, kh = tap >> 2, kw = tap & 3;
        v = f2bf(w[(((long)co * 3 + ci) * 4 + kh) * 4 + kw]);
    }
    wt[(long)co * 64 + k] = v;
}

// --- enc1 im2col: x NCHW fp32 -> A0[pos][64] bf16 (48 patch vals + 16 zeros)
__global__ __launch_bounds__(256) void xpack_kernel(const float* __restrict__ x,
                                                    bfraw* __restrict__ a0) {
    int pos = blockIdx.x * 256 + threadIdx.x;        // 262144
    int ow = pos & 127, oh = (pos >> 7) & 127, n = pos >> 14;
    __align__(16) bfraw v[64];
#pragma unroll
    for (int i = 0; i < 64; ++i) v[i] = 0;
#pragma unroll
    for (int kh = 0; kh < 4; ++kh) {
        int ih = 2 * oh - 1 + kh; if ((unsigned)ih >= 256u) continue;
#pragma unroll
        for (int kw = 0; kw < 4; ++kw) {
            int iw = 2 * ow - 1 + kw; if ((unsigned)iw >= 256u) continue;
#pragma unroll
            for (int ci = 0; ci < 3; ++ci)
                v[(kh * 4 + kw) * 3 + ci] =
                    f2bf(x[(((long)n * 3 + ci) * 256 + ih) * 256 + iw]);
        }
    }
    uint4* dst = (uint4*)(a0 + (long)pos * 64);
    const uint4* src = (const uint4*)v;
#pragma unroll
    for (int i = 0; i < 8; ++i) dst[i] = src[i];
}

// --- emb row norms
__global__ void embsq_kernel(const float* __restrict__ emb, float* __restrict__ esq) {
    int k = blockIdx.x, lane = threadIdx.x;
    float s = 0.f;
    for (int d = lane; d < 256; d += 64) { float v = emb[k * 256 + d]; s += v * v; }
    for (int o = 32; o; o >>= 1) s += __shfl_down(s, o, 64);
    if (lane == 0) esq[k] = s;
}

// ---------------------------------------------------------------------------
// MFMA implicit GEMM. C[MxN] = A[MxK]*B[KxN]. 2-phase double-buffered:
// STAGE(t+1) issued before compute(t); one barrier per K-step (its vmcnt(0)
// drain lands after the compute phase). Buffer reuse is barrier-ordered.
// ---------------------------------------------------------------------------
template<int BM, int BN, int WM, int WN, bool TR, bool RELU, bool OUTF32, bool DUALB>
__global__ __launch_bounds__(256) void igemm_kernel(
    const bfraw* __restrict__ in, const bfraw* __restrict__ wt,
    const float* __restrict__ bias, void* __restrict__ outv,
    bfraw* __restrict__ outb, const bfraw* __restrict__ zp,
    int Hin, int Win, int Cin, int sf, int NTW, int Ksteps,
    int lw, int lh, int N, int KW, int pad, int py, int px,
    unsigned long long pack)
{
    constexpr int APASS = BM / 64, BPASS = BN / 64;
    __shared__ __align__(16) bfraw ldsA[2][BM * 32];
    __shared__ __align__(16) bfraw ldsB[2][BN * 32];
    const int tid = threadIdx.x, lane = tid & 63, wv = tid >> 6;
    const int wm = wv / WN, wn = wv % WN;
    const int lrow = lane >> 2, lkof = (lane & 3) * 8;
    const int blockM = blockIdx.x, n0 = blockIdx.y * BN;
    const int Wm1 = (1 << lw) - 1, Hm1 = (1 << lh) - 1;

    long baseA[APASS]; int ihb[APASS], iwb[APASS];
#pragma unroll
    for (int p = 0; p < APASS; ++p) {
        int m = p * 64 + wv * 16 + lrow;
        int pos = blockM * BM + m;
        int ow = pos & Wm1; int t = pos >> lw;
        int oh = t & Hm1;   int nb = t >> lh;
        ihb[p] = oh * sf; iwb[p] = ow * sf;
        baseA[p] = ((long)(nb * Hin + ihb[p]) * Win + iwb[p]) * (long)Cin + lkof;
    }
    long baseB[BPASS];
#pragma unroll
    for (int p = 0; p < BPASS; ++p) {
        int nl = p * 64 + wv * 16 + lrow;
        baseB[p] = (long)(n0 + nl) * ((long)NTW * Cin) + lkof;
    }

    f32x4 acc[4][4];
#pragma unroll
    for (int i = 0; i < 4; ++i)
#pragma unroll
        for (int j = 0; j < 4; ++j) acc[i][j] = (f32x4)0.f;

    int ci0 = 0, tslot = 0, dy, dx, wk;
    if (TR) {
        unsigned e = (unsigned)pack & 0xFFFFu;
        dy = (int)((e >> 8) & 3) - 1; dx = (int)((e >> 4) & 3) - 1; wk = (int)(e & 15u);
    } else { dy = -pad; dx = -pad; wk = 0; }

    const int quad = lane >> 4, r16 = lane & 15;

    // ---- stage helper (issues APASS+BPASS async loads into buf) ----
    auto stage = [&](int buf) {
        long offA = ((long)(dy * Win + dx)) * Cin + ci0;
        long offB = (long)wk * Cin + ci0;
#pragma unroll
        for (int p = 0; p < APASS; ++p) {
            int ih = ihb[p] + dy, iw = iwb[p] + dx;
            bool ok = ((unsigned)ih < (unsigned)Hin) & ((unsigned)iw < (unsigned)Win);
            const bfraw* g = ok ? (in + baseA[p] + offA) : (zp + lkof);
            gl_lds16(g, &ldsA[buf][(p * 64 + wv * 16) * 32]);
        }
#pragma unroll
        for (int p = 0; p < BPASS; ++p)
            gl_lds16(wt + baseB[p] + offB, &ldsB[buf][(p * 64 + wv * 16) * 32]);
    };
    auto advance = [&]() {
        ci0 += 32;
        if (ci0 == Cin) {
            ci0 = 0; ++tslot;
            if (TR) {
                unsigned e = (unsigned)(pack >> ((tslot & 3) * 16)) & 0xFFFFu;
                dy = (int)((e >> 8) & 3) - 1; dx = (int)((e >> 4) & 3) - 1; wk = (int)(e & 15u);
            } else { ++wk; ++dx; if (dx == KW - pad) { dx = -pad; ++dy; } }
        }
    };

    // prologue: stage K-step 0
    stage(0); advance();
    __syncthreads();                         // vmcnt(0): buf0 resident

    for (int ks = 0; ks < Ksteps; ++ks) {
        const int cur = ks & 1;
        if (ks + 1 < Ksteps) { stage(cur ^ 1); advance(); }   // issue-early
        s16x8 af[4], bf[4];
#pragma unroll
        for (int i = 0; i < 4; ++i)
            af[i] = *(const s16x8*)&ldsA[cur][(wm * 64 + i * 16 + r16) * 32 + quad * 8];
#pragma unroll
        for (int j = 0; j < 4; ++j)
            bf[j] = *(const s16x8*)&ldsB[cur][(wn * 64 + j * 16 + r16) * 32 + quad * 8];
#pragma unroll
        for (int i = 0; i < 4; ++i)
#pragma unroll
            for (int j = 0; j < 4; ++j)
                acc[i][j] = __builtin_amdgcn_mfma_f32_16x16x32_bf16(af[i], bf[j], acc[i][j], 0, 0, 0);
        __syncthreads();                     // drain stage(ks+1) + guard buf reuse
    }

#pragma unroll
    for (int j = 0; j < 4; ++j) {
        int col = wn * 64 + j * 16 + r16; int ng = n0 + col;
        float bv = bias[ng];
#pragma unroll
        for (int i = 0; i < 4; ++i) {
            int mb = wm * 64 + i * 16 + quad * 4;
#pragma unroll
            for (int r = 0; r < 4; ++r) {
                int pos2 = blockM * BM + mb + r;
                long oaddr;
                if (TR) {
                    int ow2 = pos2 & Wm1; int t = pos2 >> lw;
                    int oh2 = t & Hm1;    int nb = t >> lh;
                    int oh = 2 * oh2 + py, ow = 2 * ow2 + px;
                    oaddr = ((long)(((nb << (lh + 1)) + oh) << (lw + 1)) + ow) * N + ng;
                } else {
                    oaddr = (long)pos2 * N + ng;
                }
                float v = acc[i][j][r] + bv;
                if (RELU) v = fmaxf(v, 0.f);
                if (OUTF32) {
                    ((float*)outv)[oaddr] = v;
                    if (DUALB) outb[oaddr] = f2bf(v);
                } else {
                    ((bfraw*)outv)[oaddr] = f2bf(v);
                }
            }
        }
    }
}

// ---------------------------------------------------------------------------
// dec2m: convT k3 s1 p1, 64->3ch via MFMA. Block = 16x16 output tile (grid
// 4096), 4 waves. Halo 18x18x64 staged once (px&7 sub-slot swizzle, as R6
// dec2). B = wb2[16][576] staged once, col&7 swizzled. Then 18 ksteps
// (tap, ci-half) x (4 A ds_read_b128 + 1 B read + 4 mfma_16x16x32_bf16)
// per wave, no barriers. A-frag: row r16 -> px (wv*4+i, r16); k = quad*8.
// C: row quad*4+r, col r16 = co. Lanes r16<3 write fp32 NCHW planes + bias.
// ---------------------------------------------------------------------------
__global__ __launch_bounds__(256) void dec2m_kernel(
    const bfraw* __restrict__ in, const bfraw* __restrict__ wb2,
    const float* __restrict__ bias, float* __restrict__ out,
    const bfraw* __restrict__ zp) {
    __shared__ __align__(16) bfraw tile[18 * 18 * 64];   // 41,472 B
    __shared__ __align__(16) bfraw ldsB[16 * 576];       // 18,432 B
    const int tid = threadIdx.x;
    const int b = blockIdx.x;
    const int n = b >> 8, t8 = b & 255;
    const int r0 = (t8 >> 4) * 16, c0 = (t8 & 15) * 16;
    const int wv = tid >> 6, lane = tid & 63;
    const int quad = lane >> 4, r16 = lane & 15;
    const long nbase = (long)n * 65536;

    // ---- stage halo: 2592 segs of 16B (identical to R6 dec2) ----
#pragma unroll
    for (int k = 0; k < 10; ++k) {
        int t = k * 256 + tid;
        int px = t >> 3, d = t & 7;
        int pr = px / 18, pc = px - pr * 18;
        int ih = r0 - 1 + pr, iw = c0 - 1 + pc;
        bool ok = ((unsigned)ih < 256u) & ((unsigned)iw < 256u);
        int s = d ^ (px & 7);                            // pre-swizzled source sub-seg
        const bfraw* g = ok ? in + ((nbase + (long)ih * 256 + iw) << 6) + s * 8 : zp;
        gl_lds16(g, &tile[(k * 256 + wv * 64) * 8]);
    }
    if (tid < 32) {
        int t = 2560 + tid;
        int px = t >> 3, d = t & 7;
        int pr = px / 18, pc = px - pr * 18;
        int ih = r0 - 1 + pr, iw = c0 - 1 + pc;
        bool ok = ((unsigned)ih < 256u) & ((unsigned)iw < 256u);
        int s = d ^ (px & 7);
        const bfraw* g = ok ? in + ((nbase + (long)ih * 256 + iw) << 6) + s * 8 : zp;
        gl_lds16(g, &tile[2560 * 8]);
    }
    // ---- stage B: 1152 segs of 16B; LDS slot (c,s) <- global seg s^(c&7) ----
#pragma unroll
    for (int k = 0; k < 4; ++k) {
        int t = k * 256 + tid;
        int c = t / 72, s = t - c * 72;
        gl_lds16(wb2 + (long)c * 576 + ((s ^ (c & 7)) << 3), &ldsB[(k * 256 + wv * 64) * 8]);
    }
    if (tid < 128) {
        int t = 1024 + tid;
        int c = t / 72, s = t - c * 72;
        gl_lds16(wb2 + (long)c * 576 + ((s ^ (c & 7)) << 3), &ldsB[(1024 + wv * 64) * 8]);
    }
    __syncthreads();   // drains vmcnt: halo + B resident

    f32x4 acc[4];
#pragma unroll
    for (int i = 0; i < 4; ++i) acc[i] = (f32x4)0.f;

    int qb[4];
#pragma unroll
    for (int i = 0; i < 4; ++i) qb[i] = (wv * 4 + i + 1) * 18 + (r16 + 1);

#pragma unroll
    for (int ks = 0; ks < 18; ++ks) {
        const int tap = ks >> 1, h = ks & 1;
        const int dy = tap / 3 - 1, dx = tap % 3 - 1;
        s16x8 bfr = *(const s16x8*)&ldsB[r16 * 576 + (((ks * 4 + quad) ^ (r16 & 7)) << 3)];
        s16x8 afr[4];
#pragma unroll
        for (int i = 0; i < 4; ++i) {
            int q = qb[i] + dy * 18 + dx;
            afr[i] = *(const s16x8*)&tile[(q << 6) + ((((h << 2) + quad) ^ (q & 7)) << 3)];
        }
#pragma unroll
        for (int i = 0; i < 4; ++i)
            acc[i] = __builtin_amdgcn_mfma_f32_16x16x32_bf16(afr[i], bfr, acc[i], 0, 0, 0);
    }

    // ---- epilogue: col r16 = co (0..2 real); row = quad*4 + r ----
    if (r16 < 3) {
        float bv = bias[r16];
        float* plane = out + (((long)(n * 3 + r16)) << 16);
#pragma unroll
        for (int i = 0; i < 4; ++i) {
            int oh = r0 + wv * 4 + i;
#pragma unroll
            for (int r = 0; r < 4; ++r) {
                int ow = c0 + quad * 4 + r;
                plane[((long)oh << 8) + ow] = acc[i][r] + bv;
            }
        }
    }
}

// ---------------------------------------------------------------------------
// VQ partial argmin: grid (512 row-blocks x 4 code-chunks). Block = 128 rows
// x 128 codes, K=256 via 8 ksteps of the R6-proven 2-barrier staged loop
// (18.6 KB LDS -> 4 blocks/CU). dist = ||e||^2 - 2*S; per-lane strict-< in
// ascending code order, 16-lane shuffle reduce, cross-half LDS merge, then
// ONE (val,key) partial per row to pb[chunk*65536 + pos].
// ---------------------------------------------------------------------------
__global__ __launch_bounds__(256) void vqm_kernel(
    const bfraw* __restrict__ zeb, const bfraw* __restrict__ embB,
    const float* __restrict__ esq, float2* __restrict__ pb)
{
    __shared__ __align__(16) bfraw ldsA[128 * 32];
    __shared__ __align__(16) bfraw ldsB[128 * 32];
    __shared__ float sEsq[128];
    __shared__ float sVal[2][128];
    __shared__ int   sKey[2][128];
    const int tid = threadIdx.x, lane = tid & 63, wv = tid >> 6;
    const int wm = wv >> 1, wn = wv & 1;
    const int lrow = lane >> 2, lkof = (lane & 3) * 8;
    const int quad = lane >> 4, r16 = lane & 15;
    const int posBase = blockIdx.x * 128;
    const int codeBase = blockIdx.y * 128;

    if (tid < 128) sEsq[tid] = esq[codeBase + tid];

    const long baseA0 = (long)(posBase + wv * 16 + lrow) * 256 + lkof;
    const long baseA1 = baseA0 + 64 * 256;
    const long baseB0 = (long)(codeBase + wv * 16 + lrow) * 256 + lkof;
    const long baseB1 = baseB0 + 64 * 256;

    f32x4 acc[4][4];
#pragma unroll
    for (int i = 0; i < 4; ++i)
#pragma unroll
        for (int j = 0; j < 4; ++j) acc[i][j] = (f32x4)0.f;

    for (int k = 0; k < 8; ++k) {
        gl_lds16(zeb + baseA0 + k * 32, &ldsA[(wv * 16) * 32]);
        gl_lds16(zeb + baseA1 + k * 32, &ldsA[(64 + wv * 16) * 32]);
        gl_lds16(embB + baseB0 + k * 32, &ldsB[(wv * 16) * 32]);
        gl_lds16(embB + baseB1 + k * 32, &ldsB[(64 + wv * 16) * 32]);
        __syncthreads();
        s16x8 af[4], bf[4];
#pragma unroll
        for (int i = 0; i < 4; ++i)
            af[i] = *(const s16x8*)&ldsA[(wm * 64 + i * 16 + r16) * 32 + quad * 8];
#pragma unroll
        for (int j = 0; j < 4; ++j)
            bf[j] = *(const s16x8*)&ldsB[(wn * 64 + j * 16 + r16) * 32 + quad * 8];
#pragma unroll
        for (int i = 0; i < 4; ++i)
#pragma unroll
            for (int j = 0; j < 4; ++j)
                acc[i][j] = __builtin_amdgcn_mfma_f32_16x16x32_bf16(af[i], bf[j], acc[i][j], 0, 0, 0);
        __syncthreads();
    }

    // epilogue: dist + argmin. C row = i*16 + quad*4 + r (in wm half), col = r16.
#pragma unroll
    for (int i = 0; i < 4; ++i) {
#pragma unroll
        for (int r = 0; r < 4; ++r) {
            float v = 1e30f; int kk = 1 << 30;
#pragma unroll
            for (int j = 0; j < 4; ++j) {           // j ascending -> codes ascending
                int code = codeBase + wn * 64 + j * 16 + r16;
                float d = sEsq[wn * 64 + j * 16 + r16] - 2.f * acc[i][j][r];
                if (d < v) { v = d; kk = code; }    // strict < keeps first index
            }
#pragma unroll
            for (int m = 1; m < 16; m <<= 1) {
                float ov = __shfl_xor(v, m, 64);
                int   ok = __shfl_xor(kk, m, 64);
                if (ov < v || (ov == v && ok < kk)) { v = ov; kk = ok; }
            }
            if (r16 == 0) {
                int localRow = wm * 64 + i * 16 + quad * 4 + r;
                sVal[wn][localRow] = v;
                sKey[wn][localRow] = kk;
            }
        }
    }
    __syncthreads();
    // merge halves: one (val,key) partial per row for this code chunk
    if (tid < 128) {
        float v0 = sVal[0][tid]; int k0 = sKey[0][tid];
        float v1 = sVal[1][tid]; int k1 = sKey[1][tid];
        bool take1 = (v1 < v0) || (v1 == v0 && k1 < k0);
        float2 p; p.x = take1 ? v1 : v0;
        p.y = __int_as_float(take1 ? k1 : k0);
        pb[(long)blockIdx.y * 65536 + posBase + tid] = p;
    }
}

// ---------------------------------------------------------------------------
// VQ merge + gather: 2048 blocks x 32 px. Merge the 4 chunk partials
// (ascending chunk order + key tie-break -> global first-min), one hist
// atomic per px, then stream zq (fp32) + zqb (bf16) at full write BW.
// ---------------------------------------------------------------------------
__global__ __launch_bounds__(256) void vqg_kernel(
    const float2* __restrict__ pb, const float* __restrict__ emb,
    float* __restrict__ zq, bfraw* __restrict__ zqb, int* __restrict__ hist)
{
    __shared__ int sIdxL[32];
    const int tid = threadIdx.x;
    const int posBase = blockIdx.x * 32;
    if (tid < 32) {
        float bv = 1e30f; int bk = 1 << 30;
#pragma unroll
        for (int c = 0; c < 4; ++c) {
            float2 p = pb[(long)c * 65536 + posBase + tid];
            int k = __float_as_int(p.y);
            if (p.x < bv || (p.x == bv && k < bk)) { bv = p.x; bk = k; }
        }
        sIdxL[tid] = bk;
        atomicAdd(&hist[bk], 1);
    }
    __syncthreads();
    const float4* emb4 = (const float4*)emb;
    float4*  zq4  = (float4*)(zq + (long)posBase * 256);
    ushort4* zqb4 = (ushort4*)(zqb + (long)posBase * 256);
#pragma unroll
    for (int it = 0; it < 8; ++it) {
        int i2 = it * 256 + tid;
        int p = i2 >> 6, c = i2 & 63;
        float4 vv = emb4[(long)sIdxL[p] * 64 + c];
        zq4[i2] = vv;
        ushort4 u; u.x = f2bf(vv.x); u.y = f2bf(vv.y); u.z = f2bf(vv.z); u.w = f2bf(vv.w);
        zqb4[i2] = u;
    }
}

// --- perplexity
__global__ void ppl_kernel(const int* __restrict__ hist, float* __restrict__ outp) {
    __shared__ float red[512];
    int t = threadIdx.x;
    float p = (float)hist[t] * (1.0f / 65536.0f);
    red[t] = p * logf(p + 1e-10f);
    __syncthreads();
    for (int s = 256; s; s >>= 1) { if (t < s) red[t] += red[t + s]; __syncthreads(); }
    if (t == 0) *outp = expf(-red[0]);
}

// host: pack convT parity-class tap table (4 entries x 16 bits)
static unsigned long long packFor(int py, int px) {
    unsigned long long pk = 0; int s = 0;
    for (int kh = 0; kh < 4; ++kh) {
        if (((py + 1 - kh) & 1) != 0) continue;
        int dy = (py + 1 - kh) / 2;
        for (int kw = 0; kw < 4; ++kw) {
            if (((px + 1 - kw) & 1) != 0) continue;
            int dx = (px + 1 - kw) / 2;
            unsigned e = ((unsigned)(dy + 1) << 8) | ((unsigned)(dx + 1) << 4) | (unsigned)(kh * 4 + kw);
            pk |= (unsigned long long)e << (16 * s); ++s;
        }
    }
    return pk;
}

extern "C" void kernel_launch(void* const* d_in, const int* in_sizes, int n_in,
                              void* d_out, int out_size, void* d_ws, size_t ws_size,
                              hipStream_t stream) {
    const float* x       = (const float*)d_in[0];
    const float* w_enc1  = (const float*)d_in[1];
    const float* b_enc1  = (const float*)d_in[2];
    const float* w_enc2  = (const float*)d_in[3];
    const float* b_enc2  = (const float*)d_in[4];
    const float* w_prevq = (const float*)d_in[5];
    const float* b_prevq = (const float*)d_in[6];
    const float* emb     = (const float*)d_in[7];
    const float* w_post  = (const float*)d_in[8];
    const float* b_post  = (const float*)d_in[9];
    const float* w_dec1  = (const float*)d_in[10];
    const float* b_dec1  = (const float*)d_in[11];
    const float* w_dec2  = (const float*)d_in[12];
    const float* b_dec2  = (const float*)d_in[13];

    float* out = (float*)d_out;
    float* xr  = out;                     // 3,145,728
    float* ze  = out + 3145728;           // 16,777,216
    float* zq  = ze + 16777216;           // 16,777,216
    float* ppl = zq + 16777216;           // 1

    // ---- workspace carve (bytes) ----
    char* W = (char*)d_ws;
    float* esq  = (float*)(W + 24576);      // 2 KB
    int*   hist = (int*)(W + 28672);        // 2 KB
    bfraw* zp   = (bfraw*)(W + 32768);      // zero page, 256 B
    bfraw* wb2  = (bfraw*)(W + 262144);     // dec2 bf16 [16][576]       18.4 KB
    bfraw* w2b  = (bfraw*)(W + 560128);     // enc2  bf16 [co][16][64]   256 KB
    bfraw* w3b  = (bfraw*)(W + 822272);     // prevq bf16 [co][9][128]   576 KB
    bfraw* wpb  = (bfraw*)(W + 1412096);    // post  bf16 [co][16][256]  1 MB
    bfraw* wd1b = (bfraw*)(W + 2460672);    // dec1  bf16 [co][16][128]  256 KB
    bfraw* wb1  = (bfraw*)(W + 2722816);    // enc1  bf16 [co][64]        8 KB
    bfraw* embB = (bfraw*)(W + 2736128);    // emb   bf16 [512][256]    256 KB
    // bufX (128 MiB @ +4 MiB): sequential lifetimes
    //   a0 [0,33.5M) -> h2 [0,16.8M) -> zeb [16.8M,50.3M) -> zqb [50.3M,83.9M)
    //   -> ddec1 [0,134.2M). pb (2 MB) lives at bufX+0 during VQ (a0/h2 dead).
    char* bufX = W + 4194304;
    bfraw* a0    = (bfraw*)bufX;
    bfraw* h2    = (bfraw*)bufX;
    bfraw* zeb   = (bfraw*)(bufX + 16777216);
    bfraw* zqb   = (bfraw*)(bufX + 50331648);
    bfraw* ddec1 = (bfraw*)bufX;
    float2* pb   = (float2*)bufX;           // 4*65536*8 B = 2 MB (VQ partials)
    // bufY (67.1 MB): dpost
    bfraw* dpost = (bfraw*)(W + 138412032);
    bfraw* h1    = (bfraw*)ze;              // alias: h1 dies before prevq writes z_e

    // ---- weight transforms + precomputes ----
    wb2_kernel<<<36, 256, 0, stream>>>(w_dec2, wb2);
    wb1_kernel<<<16, 256, 0, stream>>>(w_enc1, wb1);
    wtb_kernel<<<512, 256, 0, stream>>>(w_enc2, w2b, 128, 64, 4, 4, 0);
    wtb_kernel<<<1152, 256, 0, stream>>>(w_prevq, w3b, 256, 128, 3, 3, 0);
    wtb_kernel<<<2048, 256, 0, stream>>>(w_post, wpb, 128, 256, 4, 4, 1);
    wtb_kernel<<<512, 256, 0, stream>>>(w_dec1, wd1b, 64, 128, 4, 4, 1);
    wtb_kernel<<<512, 256, 0, stream>>>(emb, embB, 512, 256, 1, 1, 0);
    embsq_kernel<<<512, 64, 0, stream>>>(emb, esq);
    hipMemsetAsync(hist, 0, 512 * sizeof(int), stream);
    hipMemsetAsync(zp, 0, 256, stream);

    // ---- encoder ----
    xpack_kernel<<<1024, 256, 0, stream>>>(x, a0);
    igemm_kernel<256, 64, 4, 1, false, true, false, false><<<dim3(1024, 1), 256, 0, stream>>>(
        a0, wb1, b_enc1, h1, nullptr, zp, 512, 512, 64, 1, 1, 2, 9, 9, 64, 1, 0, 0, 0, 0ULL);
    igemm_kernel<128, 128, 2, 2, false, true, false, false><<<dim3(512, 1), 256, 0, stream>>>(
        h1, w2b, b_enc2, h2, nullptr, zp, 128, 128, 64, 2, 16, 32, 6, 6, 128, 4, 1, 0, 0, 0ULL);
    // prevq: dual output ze fp32 + zeb bf16
    igemm_kernel<128, 128, 2, 2, false, false, true, true><<<dim3(512, 2), 256, 0, stream>>>(
        h2, w3b, b_prevq, ze, zeb, zp, 64, 64, 128, 1, 9, 36, 6, 6, 256, 3, 1, 0, 0, 0ULL);

    // ---- VQ: partial argmin (512x4 blocks) -> merge+gather (2048 blocks) ----
    vqm_kernel<<<dim3(512, 4), 256, 0, stream>>>(zeb, embB, esq, pb);
    vqg_kernel<<<2048, 256, 0, stream>>>(pb, emb, zq, zqb, hist);
    ppl_kernel<<<1, 512, 0, stream>>>(hist, ppl);

    // ---- decoder ----
    for (int cls = 0; cls < 4; ++cls) {
        int py = cls >> 1, px = cls & 1;
        igemm_kernel<128, 128, 2, 2, true, false, false, false><<<dim3(512, 1), 256, 0, stream>>>(
            zqb, wpb, b_post, dpost, nullptr, zp, 64, 64, 256, 1, 16, 32, 6, 6, 128, 4, 1,
            py, px, packFor(py, px));
    }
    for (int cls = 0; cls < 4; ++cls) {
        int py = cls >> 1, px = cls & 1;
        igemm_kernel<256, 64, 4, 1, true, true, false, false><<<dim3(1024, 1), 256, 0, stream>>>(
            dpost, wd1b, b_dec1, ddec1, nullptr, zp, 128, 128, 128, 1, 16, 16, 7, 7, 64, 4, 1,
            py, px, packFor(py, px));
    }
    dec2m_kernel<<<4096, 256, 0, stream>>>(ddec1, wb2, b_dec2, xr, zp);
}

// Round 7
// 756.871 us; speedup vs baseline: 1.2532x; 1.1064x over previous
//
#include <hip/hip_runtime.h>
#include <stdint.h>

// ---------------------------------------------------------------------------
// VQ-VAE forward on MI355X. Round 11: igemm grid restructure. R10's 2-phase
// gave -6% (not m196's -28%: our GEMMs are small-N memory-streams, TLP had
// already hidden latency). Remaining faults are launch-shape: (1) post ran
// 4 serial 512-block dispatches = 2 blocks/CU vs ~3-4 cap + 4 tails; dec1
// likewise 4 tails. (2) no XCD L2 locality: adjacent blockM share conv tap
// rows but round-robin across 8 XCD L2s. R11: post/dec1 merged via
// blockIdx.z (one dispatch each, per-class pack as 4 args), and bijective
// XCD swizzle blockM=(bid&7)*(nwg/8)+(bid>>3) on all igemm grids (%8==0).
// Numerics bit-identical. vqm/vqg/dec2m unchanged.
// ---------------------------------------------------------------------------

typedef unsigned short bfraw;
typedef __attribute__((ext_vector_type(8))) short s16x8;
typedef __attribute__((ext_vector_type(4))) float f32x4;

__device__ __forceinline__ float bflo(unsigned int u) {
    union { unsigned int i; float f; } v; v.i = u << 16; return v.f;
}
__device__ __forceinline__ float bfhi(unsigned int u) {
    union { unsigned int i; float f; } v; v.i = u & 0xFFFF0000u; return v.f;
}
__device__ __forceinline__ bfraw f2bf(float f) {
    union { float f; unsigned int i; } v; v.f = f;
    unsigned int r = v.i + 0x7FFFu + ((v.i >> 16) & 1u);   // RNE
    return (bfraw)(r >> 16);
}

// async 16B global->LDS. LDS dest: wave-uniform base + lane*16; global src per-lane.
__device__ __forceinline__ void gl_lds16(const void* g, void* l) {
    auto gp = reinterpret_cast<const __attribute__((address_space(1))) unsigned int*>(
        reinterpret_cast<uintptr_t>(g));
    auto lp = reinterpret_cast<__attribute__((address_space(3))) unsigned int*>(
        reinterpret_cast<uintptr_t>(l));
    __builtin_amdgcn_global_load_lds(gp, lp, 16, 0, 0);
}

// --- weight transform (bf16, [co][tap][ci]) for MFMA convs (B as [n][k]);
//     with KH=KW=1 also converts emb[512][256] to bf16 B layout.
__global__ void wtb_kernel(const float* __restrict__ w, bfraw* __restrict__ wt,
                           int Cout, int Cin, int KH, int KW, int transposed) {
    int n = Cout * Cin * KH * KW;
    int NT = KH * KW;
    for (int i = blockIdx.x * blockDim.x + threadIdx.x; i < n; i += gridDim.x * blockDim.x) {
        int ci = i % Cin; int t = i / Cin;
        int tap = t % NT; int co = t / NT;
        int kh = tap / KW, kw = tap % KW;
        float v = transposed ? w[(((long)ci * Cout + co) * KH + kh) * KW + kw]
                             : w[(((long)co * Cin + ci) * KH + kh) * KW + kw];
        wt[i] = f2bf(v);
    }
}

// --- dec2 weight pack: wb2[16][576] bf16, B[co][tap*64+ci]; rows 3..15 zero.
//     convT k3 p1 == conv with wf[co][ci][kh'][kw'] = w[ci][co][2-kh'][2-kw'].
__global__ void wb2_kernel(const float* __restrict__ w, bfraw* __restrict__ wt) {
    int i = blockIdx.x * 256 + threadIdx.x;   // 9216 = 16*576
    if (i >= 9216) return;
    int ci = i & 63; int t = i >> 6;          // t = co*9 + tap
    int tap = t % 9, co = t / 9;
    bfraw v = 0;
    if (co < 3) {
        int kh = 2 - tap / 3, kw = 2 - tap % 3;
        v = f2bf(w[(((long)ci * 3 + co) * 3 + kh) * 3 + kw]);
    }
    wt[(long)co * 576 + tap * 64 + ci] = v;
}

// --- enc1 weight pack: wb1[co][k64], k=(kh*4+kw)*3+ci (48 real, 16 zero)
__global__ void wb1_kernel(const float* __restrict__ w, bfraw* __restrict__ wt) {
    int i = blockIdx.x * 256 + threadIdx.x;
    if (i >= 4096) return;
    int k = i & 63, co = i >> 6;
    bfraw v = 0;
    if (k < 48) {
        int ci = k % 3, tap = k / 3, kh = tap >> 2, kw = tap & 3;
        v = f2bf(w[(((long)co * 3 + ci) * 4 + kh) * 4 + kw]);
    }
    wt[(long)co * 64 + k] = v;
}

// --- enc1 im2col: x NCHW fp32 -> A0[pos][64] bf16 (48 patch vals + 16 zeros)
__global__ __launch_bounds__(256) void xpack_kernel(const float* __restrict__ x,
                                                    bfraw* __restrict__ a0) {
    int pos = blockIdx.x * 256 + threadIdx.x;        // 262144
    int ow = pos & 127, oh = (pos >> 7) & 127, n = pos >> 14;
    __align__(16) bfraw v[64];
#pragma unroll
    for (int i = 0; i < 64; ++i) v[i] = 0;
#pragma unroll
    for (int kh = 0; kh < 4; ++kh) {
        int ih = 2 * oh - 1 + kh; if ((unsigned)ih >= 256u) continue;
#pragma unroll
        for (int kw = 0; kw < 4; ++kw) {
            int iw = 2 * ow - 1 + kw; if ((unsigned)iw >= 256u) continue;
#pragma unroll
            for (int ci = 0; ci < 3; ++ci)
                v[(kh * 4 + kw) * 3 + ci] =
                    f2bf(x[(((long)n * 3 + ci) * 256 + ih) * 256 + iw]);
        }
    }
    uint4* dst = (uint4*)(a0 + (long)pos * 64);
    const uint4* src = (const uint4*)v;
#pragma unroll
    for (int i = 0; i < 8; ++i) dst[i] = src[i];
}

// --- emb row norms
__global__ void embsq_kernel(const float* __restrict__ emb, float* __restrict__ esq) {
    int k = blockIdx.x, lane = threadIdx.x;
    float s = 0.f;
    for (int d = lane; d < 256; d += 64) { float v = emb[k * 256 + d]; s += v * v; }
    for (int o = 32; o; o >>= 1) s += __shfl_down(s, o, 64);
    if (lane == 0) esq[k] = s;
}

// ---------------------------------------------------------------------------
// MFMA implicit GEMM. C[MxN] = A[MxK]*B[KxN]. 2-phase double-buffered
// (STAGE(t+1) before compute(t), one barrier per K-step). blockIdx.z = convT
// parity class (packs pk0..pk3, py/px derived); XCD-bijective blockM swizzle.
// ---------------------------------------------------------------------------
template<int BM, int BN, int WM, int WN, bool TR, bool RELU, bool OUTF32, bool DUALB>
__global__ __launch_bounds__(256) void igemm_kernel(
    const bfraw* __restrict__ in, const bfraw* __restrict__ wt,
    const float* __restrict__ bias, void* __restrict__ outv,
    bfraw* __restrict__ outb, const bfraw* __restrict__ zp,
    int Hin, int Win, int Cin, int sf, int NTW, int Ksteps,
    int lw, int lh, int N, int KW, int pad,
    unsigned long long pk0, unsigned long long pk1,
    unsigned long long pk2, unsigned long long pk3)
{
    constexpr int APASS = BM / 64, BPASS = BN / 64;
    __shared__ __align__(16) bfraw ldsA[2][BM * 32];
    __shared__ __align__(16) bfraw ldsB[2][BN * 32];
    const int tid = threadIdx.x, lane = tid & 63, wv = tid >> 6;
    const int wm = wv / WN, wn = wv % WN;
    const int lrow = lane >> 2, lkof = (lane & 3) * 8;
    const int n0 = blockIdx.y * BN;
    const int Wm1 = (1 << lw) - 1, Hm1 = (1 << lh) - 1;
    // XCD-bijective swizzle (gridDim.x % 8 == 0 for all launches)
    const int bid = blockIdx.x;
    const int blockM = (bid & 7) * ((int)gridDim.x >> 3) + (bid >> 3);
    // convT parity class
    const int cls = blockIdx.z;
    const unsigned long long pack = (cls == 0) ? pk0 : (cls == 1) ? pk1
                                  : (cls == 2) ? pk2 : pk3;
    const int py = cls >> 1, px = cls & 1;

    long baseA[APASS]; int ihb[APASS], iwb[APASS];
#pragma unroll
    for (int p = 0; p < APASS; ++p) {
        int m = p * 64 + wv * 16 + lrow;
        int pos = blockM * BM + m;
        int ow = pos & Wm1; int t = pos >> lw;
        int oh = t & Hm1;   int nb = t >> lh;
        ihb[p] = oh * sf; iwb[p] = ow * sf;
        baseA[p] = ((long)(nb * Hin + ihb[p]) * Win + iwb[p]) * (long)Cin + lkof;
    }
    long baseB[BPASS];
#pragma unroll
    for (int p = 0; p < BPASS; ++p) {
        int nl = p * 64 + wv * 16 + lrow;
        baseB[p] = (long)(n0 + nl) * ((long)NTW * Cin) + lkof;
    }

    f32x4 acc[4][4];
#pragma unroll
    for (int i = 0; i < 4; ++i)
#pragma unroll
        for (int j = 0; j < 4; ++j) acc[i][j] = (f32x4)0.f;

    int ci0 = 0, tslot = 0, dy, dx, wk;
    if (TR) {
        unsigned e = (unsigned)pack & 0xFFFFu;
        dy = (int)((e >> 8) & 3) - 1; dx = (int)((e >> 4) & 3) - 1; wk = (int)(e & 15u);
    } else { dy = -pad; dx = -pad; wk = 0; }

    const int quad = lane >> 4, r16 = lane & 15;

    // ---- stage helper (issues APASS+BPASS async loads into buf) ----
    auto stage = [&](int buf) {
        long offA = ((long)(dy * Win + dx)) * Cin + ci0;
        long offB = (long)wk * Cin + ci0;
#pragma unroll
        for (int p = 0; p < APASS; ++p) {
            int ih = ihb[p] + dy, iw = iwb[p] + dx;
            bool ok = ((unsigned)ih < (unsigned)Hin) & ((unsigned)iw < (unsigned)Win);
            const bfraw* g = ok ? (in + baseA[p] + offA) : (zp + lkof);
            gl_lds16(g, &ldsA[buf][(p * 64 + wv * 16) * 32]);
        }
#pragma unroll
        for (int p = 0; p < BPASS; ++p)
            gl_lds16(wt + baseB[p] + offB, &ldsB[buf][(p * 64 + wv * 16) * 32]);
    };
    auto advance = [&]() {
        ci0 += 32;
        if (ci0 == Cin) {
            ci0 = 0; ++tslot;
            if (TR) {
                unsigned e = (unsigned)(pack >> ((tslot & 3) * 16)) & 0xFFFFu;
                dy = (int)((e >> 8) & 3) - 1; dx = (int)((e >> 4) & 3) - 1; wk = (int)(e & 15u);
            } else { ++wk; ++dx; if (dx == KW - pad) { dx = -pad; ++dy; } }
        }
    };

    // prologue: stage K-step 0
    stage(0); advance();
    __syncthreads();                         // vmcnt(0): buf0 resident

    for (int ks = 0; ks < Ksteps; ++ks) {
        const int cur = ks & 1;
        if (ks + 1 < Ksteps) { stage(cur ^ 1); advance(); }   // issue-early
        s16x8 af[4], bf[4];
#pragma unroll
        for (int i = 0; i < 4; ++i)
            af[i] = *(const s16x8*)&ldsA[cur][(wm * 64 + i * 16 + r16) * 32 + quad * 8];
#pragma unroll
        for (int j = 0; j < 4; ++j)
            bf[j] = *(const s16x8*)&ldsB[cur][(wn * 64 + j * 16 + r16) * 32 + quad * 8];
#pragma unroll
        for (int i = 0; i < 4; ++i)
#pragma unroll
            for (int j = 0; j < 4; ++j)
                acc[i][j] = __builtin_amdgcn_mfma_f32_16x16x32_bf16(af[i], bf[j], acc[i][j], 0, 0, 0);
        __syncthreads();                     // drain stage(ks+1) + guard buf reuse
    }

#pragma unroll
    for (int j = 0; j < 4; ++j) {
        int col = wn * 64 + j * 16 + r16; int ng = n0 + col;
        float bv = bias[ng];
#pragma unroll
        for (int i = 0; i < 4; ++i) {
            int mb = wm * 64 + i * 16 + quad * 4;
#pragma unroll
            for (int r = 0; r < 4; ++r) {
                int pos2 = blockM * BM + mb + r;
                long oaddr;
                if (TR) {
                    int ow2 = pos2 & Wm1; int t = pos2 >> lw;
                    int oh2 = t & Hm1;    int nb = t >> lh;
                    int oh = 2 * oh2 + py, ow = 2 * ow2 + px;
                    oaddr = ((long)(((nb << (lh + 1)) + oh) << (lw + 1)) + ow) * N + ng;
                } else {
                    oaddr = (long)pos2 * N + ng;
                }
                float v = acc[i][j][r] + bv;
                if (RELU) v = fmaxf(v, 0.f);
                if (OUTF32) {
                    ((float*)outv)[oaddr] = v;
                    if (DUALB) outb[oaddr] = f2bf(v);
                } else {
                    ((bfraw*)outv)[oaddr] = f2bf(v);
                }
            }
        }
    }
}

// ---------------------------------------------------------------------------
// dec2m: convT k3 s1 p1, 64->3ch via MFMA. Block = 16x16 output tile (grid
// 4096), 4 waves. Halo 18x18x64 staged once (px&7 sub-slot swizzle, as R6
// dec2). B = wb2[16][576] staged once, col&7 swizzled. Then 18 ksteps
// (tap, ci-half) x (4 A ds_read_b128 + 1 B read + 4 mfma_16x16x32_bf16)
// per wave, no barriers. A-frag: row r16 -> px (wv*4+i, r16); k = quad*8.
// C: row quad*4+r, col r16 = co. Lanes r16<3 write fp32 NCHW planes + bias.
// ---------------------------------------------------------------------------
__global__ __launch_bounds__(256) void dec2m_kernel(
    const bfraw* __restrict__ in, const bfraw* __restrict__ wb2,
    const float* __restrict__ bias, float* __restrict__ out,
    const bfraw* __restrict__ zp) {
    __shared__ __align__(16) bfraw tile[18 * 18 * 64];   // 41,472 B
    __shared__ __align__(16) bfraw ldsB[16 * 576];       // 18,432 B
    const int tid = threadIdx.x;
    const int b = blockIdx.x;
    const int n = b >> 8, t8 = b & 255;
    const int r0 = (t8 >> 4) * 16, c0 = (t8 & 15) * 16;
    const int wv = tid >> 6, lane = tid & 63;
    const int quad = lane >> 4, r16 = lane & 15;
    const long nbase = (long)n * 65536;

    // ---- stage halo: 2592 segs of 16B (identical to R6 dec2) ----
#pragma unroll
    for (int k = 0; k < 10; ++k) {
        int t = k * 256 + tid;
        int px = t >> 3, d = t & 7;
        int pr = px / 18, pc = px - pr * 18;
        int ih = r0 - 1 + pr, iw = c0 - 1 + pc;
        bool ok = ((unsigned)ih < 256u) & ((unsigned)iw < 256u);
        int s = d ^ (px & 7);                            // pre-swizzled source sub-seg
        const bfraw* g = ok ? in + ((nbase + (long)ih * 256 + iw) << 6) + s * 8 : zp;
        gl_lds16(g, &tile[(k * 256 + wv * 64) * 8]);
    }
    if (tid < 32) {
        int t = 2560 + tid;
        int px = t >> 3, d = t & 7;
        int pr = px / 18, pc = px - pr * 18;
        int ih = r0 - 1 + pr, iw = c0 - 1 + pc;
        bool ok = ((unsigned)ih < 256u) & ((unsigned)iw < 256u);
        int s = d ^ (px & 7);
        const bfraw* g = ok ? in + ((nbase + (long)ih * 256 + iw) << 6) + s * 8 : zp;
        gl_lds16(g, &tile[2560 * 8]);
    }
    // ---- stage B: 1152 segs of 16B; LDS slot (c,s) <- global seg s^(c&7) ----
#pragma unroll
    for (int k = 0; k < 4; ++k) {
        int t = k * 256 + tid;
        int c = t / 72, s = t - c * 72;
        gl_lds16(wb2 + (long)c * 576 + ((s ^ (c & 7)) << 3), &ldsB[(k * 256 + wv * 64) * 8]);
    }
    if (tid < 128) {
        int t = 1024 + tid;
        int c = t / 72, s = t - c * 72;
        gl_lds16(wb2 + (long)c * 576 + ((s ^ (c & 7)) << 3), &ldsB[(1024 + wv * 64) * 8]);
    }
    __syncthreads();   // drains vmcnt: halo + B resident

    f32x4 acc[4];
#pragma unroll
    for (int i = 0; i < 4; ++i) acc[i] = (f32x4)0.f;

    int qb[4];
#pragma unroll
    for (int i = 0; i < 4; ++i) qb[i] = (wv * 4 + i + 1) * 18 + (r16 + 1);

#pragma unroll
    for (int ks = 0; ks < 18; ++ks) {
        const int tap = ks >> 1, h = ks & 1;
        const int dy = tap / 3 - 1, dx = tap % 3 - 1;
        s16x8 bfr = *(const s16x8*)&ldsB[r16 * 576 + (((ks * 4 + quad) ^ (r16 & 7)) << 3)];
        s16x8 afr[4];
#pragma unroll
        for (int i = 0; i < 4; ++i) {
            int q = qb[i] + dy * 18 + dx;
            afr[i] = *(const s16x8*)&tile[(q << 6) + ((((h << 2) + quad) ^ (q & 7)) << 3)];
        }
#pragma unroll
        for (int i = 0; i < 4; ++i)
            acc[i] = __builtin_amdgcn_mfma_f32_16x16x32_bf16(afr[i], bfr, acc[i], 0, 0, 0);
    }

    // ---- epilogue: col r16 = co (0..2 real); row = quad*4 + r ----
    if (r16 < 3) {
        float bv = bias[r16];
        float* plane = out + (((long)(n * 3 + r16)) << 16);
#pragma unroll
        for (int i = 0; i < 4; ++i) {
            int oh = r0 + wv * 4 + i;
#pragma unroll
            for (int r = 0; r < 4; ++r) {
                int ow = c0 + quad * 4 + r;
                plane[((long)oh << 8) + ow] = acc[i][r] + bv;
            }
        }
    }
}

// ---------------------------------------------------------------------------
// VQ partial argmin: grid (512 row-blocks x 4 code-chunks). Block = 128 rows
// x 128 codes, K=256 via 8 ksteps of the R6-proven 2-barrier staged loop
// (18.6 KB LDS -> 4 blocks/CU). dist = ||e||^2 - 2*S; per-lane strict-< in
// ascending code order, 16-lane shuffle reduce, cross-half LDS merge, then
// ONE (val,key) partial per row to pb[chunk*65536 + pos].
// ---------------------------------------------------------------------------
__global__ __launch_bounds__(256) void vqm_kernel(
    const bfraw* __restrict__ zeb, const bfraw* __restrict__ embB,
    const float* __restrict__ esq, float2* __restrict__ pb)
{
    __shared__ __align__(16) bfraw ldsA[128 * 32];
    __shared__ __align__(16) bfraw ldsB[128 * 32];
    __shared__ float sEsq[128];
    __shared__ float sVal[2][128];
    __shared__ int   sKey[2][128];
    const int tid = threadIdx.x, lane = tid & 63, wv = tid >> 6;
    const int wm = wv >> 1, wn = wv & 1;
    const int lrow = lane >> 2, lkof = (lane & 3) * 8;
    const int quad = lane >> 4, r16 = lane & 15;
    const int posBase = blockIdx.x * 128;
    const int codeBase = blockIdx.y * 128;

    if (tid < 128) sEsq[tid] = esq[codeBase + tid];

    const long baseA0 = (long)(posBase + wv * 16 + lrow) * 256 + lkof;
    const long baseA1 = baseA0 + 64 * 256;
    const long baseB0 = (long)(codeBase + wv * 16 + lrow) * 256 + lkof;
    const long baseB1 = baseB0 + 64 * 256;

    f32x4 acc[4][4];
#pragma unroll
    for (int i = 0; i < 4; ++i)
#pragma unroll
        for (int j = 0; j < 4; ++j) acc[i][j] = (f32x4)0.f;

    for (int k = 0; k < 8; ++k) {
        gl_lds16(zeb + baseA0 + k * 32, &ldsA[(wv * 16) * 32]);
        gl_lds16(zeb + baseA1 + k * 32, &ldsA[(64 + wv * 16) * 32]);
        gl_lds16(embB + baseB0 + k * 32, &ldsB[(wv * 16) * 32]);
        gl_lds16(embB + baseB1 + k * 32, &ldsB[(64 + wv * 16) * 32]);
        __syncthreads();
        s16x8 af[4], bf[4];
#pragma unroll
        for (int i = 0; i < 4; ++i)
            af[i] = *(const s16x8*)&ldsA[(wm * 64 + i * 16 + r16) * 32 + quad * 8];
#pragma unroll
        for (int j = 0; j < 4; ++j)
            bf[j] = *(const s16x8*)&ldsB[(wn * 64 + j * 16 + r16) * 32 + quad * 8];
#pragma unroll
        for (int i = 0; i < 4; ++i)
#pragma unroll
            for (int j = 0; j < 4; ++j)
                acc[i][j] = __builtin_amdgcn_mfma_f32_16x16x32_bf16(af[i], bf[j], acc[i][j], 0, 0, 0);
        __syncthreads();
    }

    // epilogue: dist + argmin. C row = i*16 + quad*4 + r (in wm half), col = r16.
#pragma unroll
    for (int i = 0; i < 4; ++i) {
#pragma unroll
        for (int r = 0; r < 4; ++r) {
            float v = 1e30f; int kk = 1 << 30;
#pragma unroll
            for (int j = 0; j < 4; ++j) {           // j ascending -> codes ascending
                int code = codeBase + wn * 64 + j * 16 + r16;
                float d = sEsq[wn * 64 + j * 16 + r16] - 2.f * acc[i][j][r];
                if (d < v) { v = d; kk = code; }    // strict < keeps first index
            }
#pragma unroll
            for (int m = 1; m < 16; m <<= 1) {
                float ov = __shfl_xor(v, m, 64);
                int   ok = __shfl_xor(kk, m, 64);
                if (ov < v || (ov == v && ok < kk)) { v = ov; kk = ok; }
            }
            if (r16 == 0) {
                int localRow = wm * 64 + i * 16 + quad * 4 + r;
                sVal[wn][localRow] = v;
                sKey[wn][localRow] = kk;
            }
        }
    }
    __syncthreads();
    // merge halves: one (val,key) partial per row for this code chunk
    if (tid < 128) {
        float v0 = sVal[0][tid]; int k0 = sKey[0][tid];
        float v1 = sVal[1][tid]; int k1 = sKey[1][tid];
        bool take1 = (v1 < v0) || (v1 == v0 && k1 < k0);
        float2 p; p.x = take1 ? v1 : v0;
        p.y = __int_as_float(take1 ? k1 : k0);
        pb[(long)blockIdx.y * 65536 + posBase + tid] = p;
    }
}

// ---------------------------------------------------------------------------
// VQ merge + gather: 2048 blocks x 32 px. Merge the 4 chunk partials
// (ascending chunk order + key tie-break -> global first-min), one hist
// atomic per px, then stream zq (fp32) + zqb (bf16) at full write BW.
// ---------------------------------------------------------------------------
__global__ __launch_bounds__(256) void vqg_kernel(
    const float2* __restrict__ pb, const float* __restrict__ emb,
    float* __restrict__ zq, bfraw* __restrict__ zqb, int* __restrict__ hist)
{
    __shared__ int sIdxL[32];
    const int tid = threadIdx.x;
    const int posBase = blockIdx.x * 32;
    if (tid < 32) {
        float bv = 1e30f; int bk = 1 << 30;
#pragma unroll
        for (int c = 0; c < 4; ++c) {
            float2 p = pb[(long)c * 65536 + posBase + tid];
            int k = __float_as_int(p.y);
            if (p.x < bv || (p.x == bv && k < bk)) { bv = p.x; bk = k; }
        }
        sIdxL[tid] = bk;
        atomicAdd(&hist[bk], 1);
    }
    __syncthreads();
    const float4* emb4 = (const float4*)emb;
    float4*  zq4  = (float4*)(zq + (long)posBase * 256);
    ushort4* zqb4 = (ushort4*)(zqb + (long)posBase * 256);
#pragma unroll
    for (int it = 0; it < 8; ++it) {
        int i2 = it * 256 + tid;
        int p = i2 >> 6, c = i2 & 63;
        float4 vv = emb4[(long)sIdxL[p] * 64 + c];
        zq4[i2] = vv;
        ushort4 u; u.x = f2bf(vv.x); u.y = f2bf(vv.y); u.z = f2bf(vv.z); u.w = f2bf(vv.w);
        zqb4[i2] = u;
    }
}

// --- perplexity
__global__ void ppl_kernel(const int* __restrict__ hist, float* __restrict__ outp) {
    __shared__ float red[512];
    int t = threadIdx.x;
    float p = (float)hist[t] * (1.0f / 65536.0f);
    red[t] = p * logf(p + 1e-10f);
    __syncthreads();
    for (int s = 256; s; s >>= 1) { if (t < s) red[t] += red[t + s]; __syncthreads(); }
    if (t == 0) *outp = expf(-red[0]);
}

// host: pack convT parity-class tap table (4 entries x 16 bits)
static unsigned long long packFor(int py, int px) {
    unsigned long long pk = 0; int s = 0;
    for (int kh = 0; kh < 4; ++kh) {
        if (((py + 1 - kh) & 1) != 0) continue;
        int dy = (py + 1 - kh) / 2;
        for (int kw = 0; kw < 4; ++kw) {
            if (((px + 1 - kw) & 1) != 0) continue;
            int dx = (px + 1 - kw) / 2;
            unsigned e = ((unsigned)(dy + 1) << 8) | ((unsigned)(dx + 1) << 4) | (unsigned)(kh * 4 + kw);
            pk |= (unsigned long long)e << (16 * s); ++s;
        }
    }
    return pk;
}

extern "C" void kernel_launch(void* const* d_in, const int* in_sizes, int n_in,
                              void* d_out, int out_size, void* d_ws, size_t ws_size,
                              hipStream_t stream) {
    const float* x       = (const float*)d_in[0];
    const float* w_enc1  = (const float*)d_in[1];
    const float* b_enc1  = (const float*)d_in[2];
    const float* w_enc2  = (const float*)d_in[3];
    const float* b_enc2  = (const float*)d_in[4];
    const float* w_prevq = (const float*)d_in[5];
    const float* b_prevq = (const float*)d_in[6];
    const float* emb     = (const float*)d_in[7];
    const float* w_post  = (const float*)d_in[8];
    const float* b_post  = (const float*)d_in[9];
    const float* w_dec1  = (const float*)d_in[10];
    const float* b_dec1  = (const float*)d_in[11];
    const float* w_dec2  = (const float*)d_in[12];
    const float* b_dec2  = (const float*)d_in[13];

    float* out = (float*)d_out;
    float* xr  = out;                     // 3,145,728
    float* ze  = out + 3145728;           // 16,777,216
    float* zq  = ze + 16777216;           // 16,777,216
    float* ppl = zq + 16777216;           // 1

    // ---- workspace carve (bytes) ----
    char* W = (char*)d_ws;
    float* esq  = (float*)(W + 24576);      // 2 KB
    int*   hist = (int*)(W + 28672);        // 2 KB
    bfraw* zp   = (bfraw*)(W + 32768);      // zero page, 256 B
    bfraw* wb2  = (bfraw*)(W + 262144);     // dec2 bf16 [16][576]       18.4 KB
    bfraw* w2b  = (bfraw*)(W + 560128);     // enc2  bf16 [co][16][64]   256 KB
    bfraw* w3b  = (bfraw*)(W + 822272);     // prevq bf16 [co][9][128]   576 KB
    bfraw* wpb  = (bfraw*)(W + 1412096);    // post  bf16 [co][16][256]  1 MB
    bfraw* wd1b = (bfraw*)(W + 2460672);    // dec1  bf16 [co][16][128]  256 KB
    bfraw* wb1  = (bfraw*)(W + 2722816);    // enc1  bf16 [co][64]        8 KB
    bfraw* embB = (bfraw*)(W + 2736128);    // emb   bf16 [512][256]    256 KB
    // bufX (128 MiB @ +4 MiB): sequential lifetimes
    //   a0 [0,33.5M) -> h2 [0,16.8M) -> zeb [16.8M,50.3M) -> zqb [50.3M,83.9M)
    //   -> ddec1 [0,134.2M). pb (2 MB) lives at bufX+0 during VQ (a0/h2 dead).
    char* bufX = W + 4194304;
    bfraw* a0    = (bfraw*)bufX;
    bfraw* h2    = (bfraw*)bufX;
    bfraw* zeb   = (bfraw*)(bufX + 16777216);
    bfraw* zqb   = (bfraw*)(bufX + 50331648);
    bfraw* ddec1 = (bfraw*)bufX;
    float2* pb   = (float2*)bufX;           // 4*65536*8 B = 2 MB (VQ partials)
    // bufY (67.1 MB): dpost
    bfraw* dpost = (bfraw*)(W + 138412032);
    bfraw* h1    = (bfraw*)ze;              // alias: h1 dies before prevq writes z_e

    // ---- weight transforms + precomputes ----
    wb2_kernel<<<36, 256, 0, stream>>>(w_dec2, wb2);
    wb1_kernel<<<16, 256, 0, stream>>>(w_enc1, wb1);
    wtb_kernel<<<512, 256, 0, stream>>>(w_enc2, w2b, 128, 64, 4, 4, 0);
    wtb_kernel<<<1152, 256, 0, stream>>>(w_prevq, w3b, 256, 128, 3, 3, 0);
    wtb_kernel<<<2048, 256, 0, stream>>>(w_post, wpb, 128, 256, 4, 4, 1);
    wtb_kernel<<<512, 256, 0, stream>>>(w_dec1, wd1b, 64, 128, 4, 4, 1);
    wtb_kernel<<<512, 256, 0, stream>>>(emb, embB, 512, 256, 1, 1, 0);
    embsq_kernel<<<512, 64, 0, stream>>>(emb, esq);
    hipMemsetAsync(hist, 0, 512 * sizeof(int), stream);
    hipMemsetAsync(zp, 0, 256, stream);

    // ---- encoder ----
    xpack_kernel<<<1024, 256, 0, stream>>>(x, a0);
    igemm_kernel<256, 64, 4, 1, false, true, false, false><<<dim3(1024, 1, 1), 256, 0, stream>>>(
        a0, wb1, b_enc1, h1, nullptr, zp, 512, 512, 64, 1, 1, 2, 9, 9, 64, 1, 0,
        0ULL, 0ULL, 0ULL, 0ULL);
    igemm_kernel<128, 128, 2, 2, false, true, false, false><<<dim3(512, 1, 1), 256, 0, stream>>>(
        h1, w2b, b_enc2, h2, nullptr, zp, 128, 128, 64, 2, 16, 32, 6, 6, 128, 4, 1,
        0ULL, 0ULL, 0ULL, 0ULL);
    // prevq: dual output ze fp32 + zeb bf16
    igemm_kernel<128, 128, 2, 2, false, false, true, true><<<dim3(512, 2, 1), 256, 0, stream>>>(
        h2, w3b, b_prevq, ze, zeb, zp, 64, 64, 128, 1, 9, 36, 6, 6, 256, 3, 1,
        0ULL, 0ULL, 0ULL, 0ULL);

    // ---- VQ: partial argmin (512x4 blocks) -> merge+gather (2048 blocks) ----
    vqm_kernel<<<dim3(512, 4), 256, 0, stream>>>(zeb, embB, esq, pb);
    vqg_kernel<<<2048, 256, 0, stream>>>(pb, emb, zq, zqb, hist);
    ppl_kernel<<<1, 512, 0, stream>>>(hist, ppl);

    // ---- decoder: 4 parity classes fused via blockIdx.z ----
    igemm_kernel<128, 128, 2, 2, true, false, false, false><<<dim3(512, 1, 4), 256, 0, stream>>>(
        zqb, wpb, b_post, dpost, nullptr, zp, 64, 64, 256, 1, 16, 32, 6, 6, 128, 4, 1,
        packFor(0, 0), packFor(0, 1), packFor(1, 0), packFor(1, 1));
    igemm_kernel<256, 64, 4, 1, true, true, false, false><<<dim3(1024, 1, 4), 256, 0, stream>>>(
        dpost, wd1b, b_dec1, ddec1, nullptr, zp, 128, 128, 128, 1, 16, 16, 7, 7, 64, 4, 1,
        packFor(0, 0), packFor(0, 1), packFor(1, 0), packFor(1, 1));
    dec2m_kernel<<<4096, 256, 0, stream>>>(ddec1, wb2, b_dec2, xr, zp);
}